// Round 3
// baseline (6000.178 us; speedup 1.0000x reference)
//
#include <hip/hip_runtime.h>
#include <hip/hip_bf16.h>
#include <cstdint>
#include <cstddef>

// ---------------------------------------------------------------------------
// Transformer encoder, 6 layers: B=2,S=2048,D=1024,H=16,HD=64,F=4096.
// bf16 MFMA GEMMs, flash attention (swapped QK^T, in-lane softmax, T2 swizzle),
// fp32 residual+LN.
// ---------------------------------------------------------------------------

typedef __bf16 bf16;
typedef __bf16 bf16x2 __attribute__((ext_vector_type(2)));
typedef __bf16 bf16x4 __attribute__((ext_vector_type(4)));
typedef __bf16 bf16x8 __attribute__((ext_vector_type(8)));
typedef float  f32x4  __attribute__((ext_vector_type(4)));

#define MFMA16(a, b, c) __builtin_amdgcn_mfma_f32_16x16x32_bf16((a), (b), (c), 0, 0, 0)

static __device__ __forceinline__ void load_lds16(const void* g, void* l) {
  __builtin_amdgcn_global_load_lds((const __attribute__((address_space(1))) void*)g,
                                   (__attribute__((address_space(3))) void*)l, 16, 0, 0);
}

// ---------------- embedding + positional encoding -> bf16 x ----------------
__global__ __launch_bounds__(256) void embed_kernel(const int* __restrict__ tok,
                                                    const float* __restrict__ emb,
                                                    bf16* __restrict__ xo) {
  const int row = blockIdx.x;          // b*2048 + s
  const int s = row & 2047;
  const int t = tok[row];
  const int d0 = threadIdx.x * 4;
  const float4 e = *(const float4*)&emb[(size_t)t * 1024 + d0];
  const float* ef = (const float*)&e;
  bf16x4 o4;
#pragma unroll
  for (int j = 0; j < 4; ++j) {
    const int d = d0 + j;
    const float div = __expf(-(float)(d & ~1) * 0.00899447301950864f); // ln(1e4)/1024
    const float arg = (float)s * div;
    const float pe = (d & 1) ? cosf(arg) : sinf(arg);
    o4[j] = (bf16)(ef[j] + pe);
  }
  *(bf16x4*)&xo[(size_t)row * 1024 + d0] = o4;
}

// ------------- weight transpose: fp32 [K][N] -> bf16 [N][K], batched --------
struct TJob { const float* src; bf16* dst; int K; int N; int t0; };
struct TArgs { TJob j[6]; };

__global__ __launch_bounds__(256) void wtrans_kernel(TArgs a) {
  __shared__ float t[32][33];
  const int blk = blockIdx.x;
  const float* src = a.j[0].src; bf16* dst = a.j[0].dst;
  int K = a.j[0].K, N = a.j[0].N, t0 = a.j[0].t0;
#pragma unroll
  for (int q = 1; q < 6; ++q)
    if (blk >= a.j[q].t0) { src = a.j[q].src; dst = a.j[q].dst; K = a.j[q].K; N = a.j[q].N; t0 = a.j[q].t0; }
  const int tj = blk - t0;
  const int tilesK = K >> 5;
  const int tk = (tj % tilesK) << 5;
  const int tn = (tj / tilesK) << 5;
  const int lx = threadIdx.x & 31, ly = threadIdx.x >> 5;
#pragma unroll
  for (int i = 0; i < 4; ++i)
    t[ly + 8 * i][lx] = src[(size_t)(tk + ly + 8 * i) * N + tn + lx];
  __syncthreads();
#pragma unroll
  for (int i = 0; i < 4; ++i)
    dst[(size_t)(tn + ly + 8 * i) * K + tk + lx] = (bf16)t[lx][ly + 8 * i];
}

// -------- V transpose per layer: [bh][s][64] bf16 -> [bh][64][s] bf16 -------
__global__ __launch_bounds__(256) void vtrans_kernel(const bf16* __restrict__ v,
                                                     bf16* __restrict__ vt) {
  __shared__ bf16 t[64][72];
  const int bh = blockIdx.y;
  const int s0 = blockIdx.x * 64;
  const int tid = threadIdx.x;
#pragma unroll
  for (int it = 0; it < 2; ++it) {
    const int idx = tid + it * 256;
    const int sr = idx >> 3, h8 = (idx & 7) * 8;
    *(bf16x8*)&t[sr][h8] = *(const bf16x8*)&v[((size_t)bh * 2048 + s0 + sr) * 64 + h8];
  }
  __syncthreads();
#pragma unroll
  for (int it = 0; it < 2; ++it) {
    const int idx = tid + it * 256;
    const int hd = idx >> 3, s8 = (idx & 7) * 8;
    bf16x8 o;
#pragma unroll
    for (int j = 0; j < 8; ++j) o[j] = t[s8 + j][hd];
    *(bf16x8*)&vt[((size_t)bh * 64 + hd) * 2048 + s0 + s8] = o;
  }
}

// ---------------- GEMM: C[M,N] = A[M,K]bf16 * Bt[N,K]bf16, 128x128 ---------
// 1D grid with XCD swizzle (grid % 8 == 0). nbx = N/128.
// EPI 0: + per-segment bias, scatter to q/k/v [B,H,S,64]
// EPI 2: + bias, ReLU -> bf16 out
template <int EPI>
__global__ __launch_bounds__(256) void gemm_bt(
    const bf16* __restrict__ A, const bf16* __restrict__ Bt, int Kk, int Nn, int nbx,
    const float* __restrict__ bias0, const float* __restrict__ bias1,
    const float* __restrict__ bias2, bf16* __restrict__ outb,
    bf16* __restrict__ q_out, bf16* __restrict__ k_out, bf16* __restrict__ v_out) {
  __shared__ __align__(16) bf16 As[128 * 32];
  __shared__ __align__(16) bf16 Bs[128 * 32];
  const int cpx = gridDim.x >> 3;
  const int wg = (blockIdx.x & 7) * cpx + (blockIdx.x >> 3);
  const int bx = wg % nbx, by = wg / nbx;
  const int tid = threadIdx.x;
  const int lane = tid & 63;
  const int wave = tid >> 6;
  const int lr = lane & 15, lg = lane >> 4;
  const int m0 = by * 128;
  const int n0 = bx * 128;
  const int wr = (wave >> 1) * 64, wc = (wave & 1) * 64;

  f32x4 acc[4][4] = {};

  const int idx0 = tid, idx1 = tid + 256;
  const char* gA0 = (const char*)(A + (size_t)(m0 + (idx0 >> 2)) * Kk) + (idx0 & 3) * 16;
  const char* gA1 = (const char*)(A + (size_t)(m0 + (idx1 >> 2)) * Kk) + (idx1 & 3) * 16;
  const char* gB0 = (const char*)(Bt + (size_t)(n0 + (idx0 >> 2)) * Kk) + (idx0 & 3) * 16;
  const char* gB1 = (const char*)(Bt + (size_t)(n0 + (idx1 >> 2)) * Kk) + (idx1 & 3) * 16;
  bf16* lA0 = &As[(wave * 64) * 8];
  bf16* lA1 = &As[(256 + wave * 64) * 8];
  bf16* lB0 = &Bs[(wave * 64) * 8];
  bf16* lB1 = &Bs[(256 + wave * 64) * 8];

  const int ksteps = Kk >> 5;
  for (int kt = 0; kt < ksteps; ++kt) {
    load_lds16(gA0, lA0); load_lds16(gA1, lA1);
    load_lds16(gB0, lB0); load_lds16(gB1, lB1);
    gA0 += 64; gA1 += 64; gB0 += 64; gB1 += 64;
    __syncthreads();
    bf16x8 af[4], bfr[4];
#pragma unroll
    for (int i = 0; i < 4; ++i)
      af[i] = *(const bf16x8*)&As[(wr + i * 16 + lr) * 32 + lg * 8];
#pragma unroll
    for (int j = 0; j < 4; ++j)
      bfr[j] = *(const bf16x8*)&Bs[(wc + j * 16 + lr) * 32 + lg * 8];
#pragma unroll
    for (int i = 0; i < 4; ++i)
#pragma unroll
      for (int j = 0; j < 4; ++j)
        acc[i][j] = MFMA16(af[i], bfr[j], acc[i][j]);
    __syncthreads();
  }

#pragma unroll
  for (int i = 0; i < 4; ++i) {
#pragma unroll
    for (int j = 0; j < 4; ++j) {
#pragma unroll
      for (int r = 0; r < 4; ++r) {
        const int row = m0 + wr + i * 16 + lg * 4 + r;
        const int col = n0 + wc + j * 16 + lr;
        float val = acc[i][j][r];
        if (EPI == 0) {
          const int which = col >> 10, hc = col & 1023;
          const float* bs = (which == 0) ? bias0 : (which == 1) ? bias1 : bias2;
          bf16* dst = (which == 0) ? q_out : (which == 1) ? k_out : v_out;
          val += bs[hc];
          const int b = row >> 11, s = row & 2047;
          const int h = hc >> 6, hd = hc & 63;
          dst[(((size_t)b * 16 + h) * 2048 + s) * 64 + hd] = (bf16)val;
        } else {
          val += bias0[col];
          outb[(size_t)row * Nn + col] = (bf16)(val > 0.f ? val : 0.f);
        }
      }
    }
  }
}

// -------- GEMM 64x64 tile (for N=1024 shapes): + bias + resid -> fp32 -------
// grid = (M/64)*(N/64) 1D, XCD-swizzled. 4 waves, each 32x32 output.
__global__ __launch_bounds__(256) void gemm64(
    const bf16* __restrict__ A, const bf16* __restrict__ Bt, int Kk, int Nn, int nbx,
    const float* __restrict__ bias0, const bf16* __restrict__ resid,
    float* __restrict__ outf) {
  __shared__ __align__(16) bf16 As[64 * 32];
  __shared__ __align__(16) bf16 Bs[64 * 32];
  const int cpx = gridDim.x >> 3;
  const int wg = (blockIdx.x & 7) * cpx + (blockIdx.x >> 3);
  const int bx = wg % nbx, by = wg / nbx;
  const int tid = threadIdx.x;
  const int lane = tid & 63;
  const int wave = tid >> 6;
  const int lr = lane & 15, lg = lane >> 4;
  const int m0 = by * 64, n0 = bx * 64;
  const int wr = (wave >> 1) * 32, wc = (wave & 1) * 32;

  f32x4 acc[2][2] = {};

  const char* gA = (const char*)(A + (size_t)(m0 + (tid >> 2)) * Kk) + (tid & 3) * 16;
  const char* gB = (const char*)(Bt + (size_t)(n0 + (tid >> 2)) * Kk) + (tid & 3) * 16;
  bf16* lA = &As[wave * 512];
  bf16* lB = &Bs[wave * 512];

  const int ksteps = Kk >> 5;
  for (int kt = 0; kt < ksteps; ++kt) {
    load_lds16(gA, lA);
    load_lds16(gB, lB);
    gA += 64; gB += 64;
    __syncthreads();
    bf16x8 af[2], bfr[2];
#pragma unroll
    for (int i = 0; i < 2; ++i)
      af[i] = *(const bf16x8*)&As[(wr + i * 16 + lr) * 32 + lg * 8];
#pragma unroll
    for (int j = 0; j < 2; ++j)
      bfr[j] = *(const bf16x8*)&Bs[(wc + j * 16 + lr) * 32 + lg * 8];
#pragma unroll
    for (int i = 0; i < 2; ++i)
#pragma unroll
      for (int j = 0; j < 2; ++j)
        acc[i][j] = MFMA16(af[i], bfr[j], acc[i][j]);
    __syncthreads();
  }

#pragma unroll
  for (int i = 0; i < 2; ++i)
#pragma unroll
    for (int j = 0; j < 2; ++j)
#pragma unroll
      for (int r = 0; r < 4; ++r) {
        const int row = m0 + wr + i * 16 + lg * 4 + r;
        const int col = n0 + wc + j * 16 + lr;
        const float val = acc[i][j][r] + bias0[col] + (float)resid[(size_t)row * Nn + col];
        outf[(size_t)row * Nn + col] = val;
      }
}

// ------------------------- flash attention (per b,h) ------------------------
// grid: (S/64, B*H). block: 256 = 4 waves; wave w owns q-rows [64*bx + 16w, +16)
// K in [bh][s][64]; V^T in [bh][64][s].
// Swapped QK^T (S^T in lanes: q=lr, keys=lg*4+r per ks-tile), log2-domain
// online softmax with defer-max, XOR-swizzled LDS (col8 ^= row&7).
__global__ __launch_bounds__(256) void attn_kernel(const bf16* __restrict__ q,
                                                   const bf16* __restrict__ k,
                                                   const bf16* __restrict__ vt,
                                                   bf16* __restrict__ ctxo) {
  __shared__ __align__(16) bf16 Kl[64][64];
  __shared__ __align__(16) bf16 Vt[64][64];   // rows = hd, cols = key
  __shared__ __align__(16) bf16 Pl[4][16][64];
  const int tid = threadIdx.x;
  const int lane = tid & 63, w = tid >> 6;
  const int lr = lane & 15, lg = lane >> 4;
  const int swz = lr & 7;
  const int bh = blockIdx.y;
  const int q0 = blockIdx.x * 64;

  // Q fragment (B-operand rows = q), pre-scaled by (1/sqrt(64))*log2(e)
  const bf16* qp = q + ((size_t)bh * 2048 + q0 + w * 16) * 64;
  bf16x8 qf0 = *(const bf16x8*)&qp[lr * 64 + lg * 8];
  bf16x8 qf1 = *(const bf16x8*)&qp[lr * 64 + lg * 8 + 32];
  const float qs = 0.18033688011112042f;
#pragma unroll
  for (int j = 0; j < 8; ++j) {
    qf0[j] = (bf16)((float)qf0[j] * qs);
    qf1[j] = (bf16)((float)qf1[j] * qs);
  }
  bf16x8 ones8;
#pragma unroll
  for (int j = 0; j < 8; ++j) ones8[j] = (bf16)1.0f;

  const bf16* kbase = k + (size_t)bh * 2048 * 64;
  const bf16* vtb = vt + (size_t)bh * 64 * 2048;

  const int sr0 = tid >> 3, sr1 = sr0 + 32;       // staging rows
  const int c0 = (tid & 7) * 8;                   // unswizzled col
  const int cs0 = c0 ^ ((sr0 & 7) << 3);          // swizzled col
  const int cs1 = c0 ^ ((sr1 & 7) << 3);

  f32x4 acc[4] = {};
  f32x4 accl = {};                                // P row-sums via ones-MFMA
  float mq = -1e30f;                              // per-lane running max (q = lr)

  bf16x8 kr[2][2], vr[2][2];
  kr[0][0] = *(const bf16x8*)&kbase[(size_t)sr0 * 64 + c0];
  kr[0][1] = *(const bf16x8*)&kbase[(size_t)sr1 * 64 + c0];
  vr[0][0] = *(const bf16x8*)&vtb[(size_t)sr0 * 2048 + c0];
  vr[0][1] = *(const bf16x8*)&vtb[(size_t)sr1 * 2048 + c0];

  for (int c = 0; c < 32; ++c) {
    const int pp = c & 1;
    *(bf16x8*)&Kl[sr0][cs0] = kr[pp][0];
    *(bf16x8*)&Kl[sr1][cs1] = kr[pp][1];
    *(bf16x8*)&Vt[sr0][cs0] = vr[pp][0];
    *(bf16x8*)&Vt[sr1][cs1] = vr[pp][1];
    if (c + 1 < 32) {                              // next-chunk loads, pre-barrier
      const int key0n = (c + 1) * 64;
      kr[pp ^ 1][0] = *(const bf16x8*)&kbase[(size_t)(key0n + sr0) * 64 + c0];
      kr[pp ^ 1][1] = *(const bf16x8*)&kbase[(size_t)(key0n + sr1) * 64 + c0];
      vr[pp ^ 1][0] = *(const bf16x8*)&vtb[(size_t)sr0 * 2048 + key0n + c0];
      vr[pp ^ 1][1] = *(const bf16x8*)&vtb[(size_t)sr1 * 2048 + key0n + c0];
    }
    __syncthreads();

    // --- swapped QK^T: st[ks][r] = S*log2e [q=lr][key = ks*16 + lg*4 + r] ---
    f32x4 st[4];
    __builtin_amdgcn_s_setprio(1);
#pragma unroll
    for (int ks = 0; ks < 4; ++ks) {
      const bf16x8 kf0 = *(const bf16x8*)&Kl[ks * 16 + lr][(lg ^ swz) << 3];
      const bf16x8 kf1 = *(const bf16x8*)&Kl[ks * 16 + lr][((lg + 4) ^ swz) << 3];
      f32x4 sa = {};
      sa = MFMA16(kf0, qf0, sa);
      sa = MFMA16(kf1, qf1, sa);
      st[ks] = sa;
    }
    __builtin_amdgcn_s_setprio(0);

    // --- in-lane online softmax (log2 domain) ---
    float mx = st[0][0];
#pragma unroll
    for (int ks = 0; ks < 4; ++ks)
#pragma unroll
      for (int r = 0; r < 4; ++r) mx = fmaxf(mx, st[ks][r]);
    mx = fmaxf(mx, __shfl_xor(mx, 16));
    mx = fmaxf(mx, __shfl_xor(mx, 32));
    if (!__all(mx - mq <= 8.0f)) {                 // defer-max (T13)
      const float resc = exp2f(mq - mx);
      mq = mx;
      float rq[4];
#pragma unroll
      for (int r = 0; r < 4; ++r) rq[r] = __shfl(resc, lg * 4 + r);
#pragma unroll
      for (int r = 0; r < 4; ++r) {
        accl[r] *= rq[r];
#pragma unroll
        for (int jn = 0; jn < 4; ++jn) acc[jn][r] *= rq[r];
      }
    }
#pragma unroll
    for (int ks = 0; ks < 4; ++ks) {               // P pack + vectorized store
      bf16x4 pk;
#pragma unroll
      for (int r = 0; r < 4; ++r) pk[r] = (bf16)exp2f(st[ks][r] - mq);
      const int col = (((ks * 2 + (lg >> 1)) ^ swz) << 3) + ((lg & 1) << 2);
      *(bf16x4*)&Pl[w][lr][col] = pk;
    }

    // --- PV + denominators ---
    const bf16x8 pf0 = *(const bf16x8*)&Pl[w][lr][(lg ^ swz) << 3];
    const bf16x8 pf1 = *(const bf16x8*)&Pl[w][lr][((lg + 4) ^ swz) << 3];
    __builtin_amdgcn_s_setprio(1);
#pragma unroll
    for (int jn = 0; jn < 4; ++jn) {
      const bf16x8 vf0 = *(const bf16x8*)&Vt[jn * 16 + lr][(lg ^ swz) << 3];
      const bf16x8 vf1 = *(const bf16x8*)&Vt[jn * 16 + lr][((lg + 4) ^ swz) << 3];
      acc[jn] = MFMA16(pf0, vf0, acc[jn]);
      acc[jn] = MFMA16(pf1, vf1, acc[jn]);
    }
    accl = MFMA16(pf0, ones8, accl);
    accl = MFMA16(pf1, ones8, accl);
    __builtin_amdgcn_s_setprio(0);
    __syncthreads();
  }

  const int bb = bh >> 4, hh = bh & 15;
#pragma unroll
  for (int r = 0; r < 4; ++r) {
    const float inv = 1.f / accl[r];
    const size_t rowg = (size_t)bb * 2048 + q0 + w * 16 + lg * 4 + r;
#pragma unroll
    for (int jn = 0; jn < 4; ++jn)
      ctxo[rowg * 1024 + hh * 64 + jn * 16 + lr] = (bf16)(acc[jn][r] * inv);
  }
}

// ------------------------------ LayerNorm -----------------------------------
__global__ __launch_bounds__(256) void ln_kernel(const float* __restrict__ y,
                                                 const float* __restrict__ g,
                                                 const float* __restrict__ be,
                                                 bf16* __restrict__ xo) {
  const int row = blockIdx.x, tid = threadIdx.x;
  const float4 v = ((const float4*)(y + (size_t)row * 1024))[tid];
  float s = v.x + v.y + v.z + v.w;
  float s2 = v.x * v.x + v.y * v.y + v.z * v.z + v.w * v.w;
#pragma unroll
  for (int o = 32; o > 0; o >>= 1) { s += __shfl_down(s, o); s2 += __shfl_down(s2, o); }
  __shared__ float red[8];
  if ((tid & 63) == 0) { red[tid >> 6] = s; red[4 + (tid >> 6)] = s2; }
  __syncthreads();
  s = red[0] + red[1] + red[2] + red[3];
  s2 = red[4] + red[5] + red[6] + red[7];
  const float mean = s * (1.f / 1024.f);
  const float var = s2 * (1.f / 1024.f) - mean * mean;
  const float rstd = rsqrtf(var + 1e-5f);
  const float4 gv = ((const float4*)g)[tid];
  const float4 bv = ((const float4*)be)[tid];
  bf16x4 o4;
  o4[0] = (bf16)((v.x - mean) * rstd * gv.x + bv.x);
  o4[1] = (bf16)((v.y - mean) * rstd * gv.y + bv.y);
  o4[2] = (bf16)((v.z - mean) * rstd * gv.z + bv.z);
  o4[3] = (bf16)((v.w - mean) * rstd * gv.w + bv.w);
  *(bf16x4*)&xo[(size_t)row * 1024 + tid * 4] = o4;
}

// ------------------------------ bf16 -> fp32 --------------------------------
__global__ __launch_bounds__(256) void to_f32_kernel(const bf16* __restrict__ x,
                                                     float* __restrict__ o) {
  const size_t i = ((size_t)blockIdx.x * 256 + threadIdx.x) * 4;
  const bf16x4 v = *(const bf16x4*)&x[i];
  float4 f;
  f.x = (float)v[0]; f.y = (float)v[1]; f.z = (float)v[2]; f.w = (float)v[3];
  *(float4*)&o[i] = f;
}

// ----------------------------------------------------------------------------
extern "C" void kernel_launch(void* const* d_in, const int* in_sizes, int n_in,
                              void* d_out, int out_size, void* d_ws, size_t ws_size,
                              hipStream_t stream) {
  const int* tokens = (const int*)d_in[0];
  const float* emb = (const float*)d_in[2];
  const float* Wq = (const float*)d_in[3];
  const float* bq = (const float*)d_in[4];
  const float* Wk = (const float*)d_in[5];
  const float* bk = (const float*)d_in[6];
  const float* Wv = (const float*)d_in[7];
  const float* bv = (const float*)d_in[8];
  const float* Wo = (const float*)d_in[9];
  const float* bo = (const float*)d_in[10];
  const float* W1 = (const float*)d_in[11];
  const float* b1 = (const float*)d_in[12];
  const float* W2 = (const float*)d_in[13];
  const float* b2 = (const float*)d_in[14];
  const float* g1 = (const float*)d_in[15];
  const float* be1 = (const float*)d_in[16];
  const float* g2 = (const float*)d_in[17];
  const float* be2 = (const float*)d_in[18];

  char* p = (char*)d_ws;
  auto carve = [&](size_t bytes) { char* r = p; p += (bytes + 255) & ~(size_t)255; return r; };
  bf16* wt_qkv = (bf16*)carve((size_t)3072 * 1024 * 2);
  bf16* wt_o   = (bf16*)carve((size_t)1024 * 1024 * 2);
  bf16* wt_1   = (bf16*)carve((size_t)4096 * 1024 * 2);
  bf16* wt_2   = (bf16*)carve((size_t)1024 * 4096 * 2);
  bf16* xb     = (bf16*)carve((size_t)4096 * 1024 * 2);
  bf16* qb     = (bf16*)carve((size_t)4096 * 1024 * 2);
  bf16* kb     = (bf16*)carve((size_t)4096 * 1024 * 2);
  bf16* vb     = (bf16*)carve((size_t)4096 * 1024 * 2);
  bf16* vtb    = (bf16*)carve((size_t)4096 * 1024 * 2);
  bf16* ctxb   = (bf16*)carve((size_t)4096 * 1024 * 2);
  float* yb    = (float*)carve((size_t)4096 * 1024 * 4);
  bf16* hb     = (bf16*)carve((size_t)4096 * 4096 * 2);

  embed_kernel<<<4096, 256, 0, stream>>>(tokens, emb, xb);

  for (int l = 0; l < 6; ++l) {
    TArgs ta;
    ta.j[0] = { Wq + (size_t)l * 1024 * 1024, wt_qkv,                  1024, 1024, 0 };
    ta.j[1] = { Wk + (size_t)l * 1024 * 1024, wt_qkv + 1024 * 1024,    1024, 1024, 1024 };
    ta.j[2] = { Wv + (size_t)l * 1024 * 1024, wt_qkv + 2 * 1024 * 1024,1024, 1024, 2048 };
    ta.j[3] = { Wo + (size_t)l * 1024 * 1024, wt_o,                    1024, 1024, 3072 };
    ta.j[4] = { W1 + (size_t)l * 1024 * 4096, wt_1,                    1024, 4096, 4096 };
    ta.j[5] = { W2 + (size_t)l * 4096 * 1024, wt_2,                    4096, 1024, 8192 };
    wtrans_kernel<<<12288, 256, 0, stream>>>(ta);

    gemm_bt<0><<<768, 256, 0, stream>>>(xb, wt_qkv, 1024, 3072, 24,
        bq + (size_t)l * 1024, bk + (size_t)l * 1024, bv + (size_t)l * 1024,
        nullptr, qb, kb, vb);

    vtrans_kernel<<<dim3(32, 32), 256, 0, stream>>>(vb, vtb);

    attn_kernel<<<dim3(32, 32), 256, 0, stream>>>(qb, kb, vtb, ctxb);

    gemm64<<<1024, 256, 0, stream>>>(ctxb, wt_o, 1024, 1024, 16,
        bo + (size_t)l * 1024, xb, yb);

    ln_kernel<<<4096, 256, 0, stream>>>(yb, g1 + (size_t)l * 1024, be1 + (size_t)l * 1024, xb);

    gemm_bt<2><<<1024, 256, 0, stream>>>(xb, wt_1, 1024, 4096, 32,
        b1 + (size_t)l * 4096, nullptr, nullptr, hb,
        nullptr, nullptr, nullptr);

    gemm64<<<1024, 256, 0, stream>>>(hb, wt_2, 4096, 1024, 16,
        b2 + (size_t)l * 1024, xb, yb);

    ln_kernel<<<4096, 256, 0, stream>>>(yb, g2 + (size_t)l * 1024, be2 + (size_t)l * 1024, xb);
  }

  to_f32_kernel<<<4096, 256, 0, stream>>>(xb, (float*)d_out);
}

// Round 4
// 1766.833 us; speedup vs baseline: 3.3960x; 3.3960x over previous
//
#include <hip/hip_runtime.h>
#include <hip/hip_bf16.h>
#include <cstdint>
#include <cstddef>

// ---------------------------------------------------------------------------
// Transformer encoder, 6 layers: B=2,S=2048,D=1024,H=16,HD=64,F=4096.
// bf16 MFMA GEMMs, flash attention (swapped QK^T, in-lane softmax, T2 swizzle),
// fp32 residual+LN.
// ---------------------------------------------------------------------------

typedef __bf16 bf16;
typedef __bf16 bf16x2 __attribute__((ext_vector_type(2)));
typedef __bf16 bf16x4 __attribute__((ext_vector_type(4)));
typedef __bf16 bf16x8 __attribute__((ext_vector_type(8)));
typedef float  f32x4  __attribute__((ext_vector_type(4)));

#define MFMA16(a, b, c) __builtin_amdgcn_mfma_f32_16x16x32_bf16((a), (b), (c), 0, 0, 0)

static __device__ __forceinline__ void load_lds16(const void* g, void* l) {
  __builtin_amdgcn_global_load_lds((const __attribute__((address_space(1))) void*)g,
                                   (__attribute__((address_space(3))) void*)l, 16, 0, 0);
}

// ---------------- embedding + positional encoding -> bf16 x ----------------
__global__ __launch_bounds__(256) void embed_kernel(const int* __restrict__ tok,
                                                    const float* __restrict__ emb,
                                                    bf16* __restrict__ xo) {
  const int row = blockIdx.x;          // b*2048 + s
  const int s = row & 2047;
  const int t = tok[row];
  const int d0 = threadIdx.x * 4;
  const float4 e = *(const float4*)&emb[(size_t)t * 1024 + d0];
  const float* ef = (const float*)&e;
  bf16x4 o4;
#pragma unroll
  for (int j = 0; j < 4; ++j) {
    const int d = d0 + j;
    const float div = __expf(-(float)(d & ~1) * 0.00899447301950864f); // ln(1e4)/1024
    const float arg = (float)s * div;
    const float pe = (d & 1) ? cosf(arg) : sinf(arg);
    o4[j] = (bf16)(ef[j] + pe);
  }
  *(bf16x4*)&xo[(size_t)row * 1024 + d0] = o4;
}

// ------------- weight transpose: fp32 [K][N] -> bf16 [N][K], batched --------
struct TJob { const float* src; bf16* dst; int K; int N; int t0; };
struct TArgs { TJob j[6]; };

__global__ __launch_bounds__(256) void wtrans_kernel(TArgs a) {
  __shared__ float t[32][33];
  const int blk = blockIdx.x;
  const float* src = a.j[0].src; bf16* dst = a.j[0].dst;
  int K = a.j[0].K, N = a.j[0].N, t0 = a.j[0].t0;
#pragma unroll
  for (int q = 1; q < 6; ++q)
    if (blk >= a.j[q].t0) { src = a.j[q].src; dst = a.j[q].dst; K = a.j[q].K; N = a.j[q].N; t0 = a.j[q].t0; }
  const int tj = blk - t0;
  const int tilesK = K >> 5;
  const int tk = (tj % tilesK) << 5;
  const int tn = (tj / tilesK) << 5;
  const int lx = threadIdx.x & 31, ly = threadIdx.x >> 5;
#pragma unroll
  for (int i = 0; i < 4; ++i)
    t[ly + 8 * i][lx] = src[(size_t)(tk + ly + 8 * i) * N + tn + lx];
  __syncthreads();
#pragma unroll
  for (int i = 0; i < 4; ++i)
    dst[(size_t)(tn + ly + 8 * i) * K + tk + lx] = (bf16)t[lx][ly + 8 * i];
}

// -------- V transpose per layer: [bh][s][64] bf16 -> [bh][64][s] bf16 -------
__global__ __launch_bounds__(256) void vtrans_kernel(const bf16* __restrict__ v,
                                                     bf16* __restrict__ vt) {
  __shared__ bf16 t[64][72];
  const int bh = blockIdx.y;
  const int s0 = blockIdx.x * 64;
  const int tid = threadIdx.x;
#pragma unroll
  for (int it = 0; it < 2; ++it) {
    const int idx = tid + it * 256;
    const int sr = idx >> 3, h8 = (idx & 7) * 8;
    *(bf16x8*)&t[sr][h8] = *(const bf16x8*)&v[((size_t)bh * 2048 + s0 + sr) * 64 + h8];
  }
  __syncthreads();
#pragma unroll
  for (int it = 0; it < 2; ++it) {
    const int idx = tid + it * 256;
    const int hd = idx >> 3, s8 = (idx & 7) * 8;
    bf16x8 o;
#pragma unroll
    for (int j = 0; j < 8; ++j) o[j] = t[s8 + j][hd];
    *(bf16x8*)&vt[((size_t)bh * 64 + hd) * 2048 + s0 + s8] = o;
  }
}

// ---------------- GEMM: C[M,N] = A[M,K]bf16 * Bt[N,K]bf16, 128x128 ---------
// 1D grid with XCD swizzle (grid % 8 == 0). nbx = N/128.
// EPI 0: + per-segment bias, scatter to q/k/v [B,H,S,64]
// EPI 2: + bias, ReLU -> bf16 out
template <int EPI>
__global__ __launch_bounds__(256) void gemm_bt(
    const bf16* __restrict__ A, const bf16* __restrict__ Bt, int Kk, int Nn, int nbx,
    const float* __restrict__ bias0, const float* __restrict__ bias1,
    const float* __restrict__ bias2, bf16* __restrict__ outb,
    bf16* __restrict__ q_out, bf16* __restrict__ k_out, bf16* __restrict__ v_out) {
  __shared__ __align__(16) bf16 As[128 * 32];
  __shared__ __align__(16) bf16 Bs[128 * 32];
  const int cpx = gridDim.x >> 3;
  const int wg = (blockIdx.x & 7) * cpx + (blockIdx.x >> 3);
  const int bx = wg % nbx, by = wg / nbx;
  const int tid = threadIdx.x;
  const int lane = tid & 63;
  const int wave = tid >> 6;
  const int lr = lane & 15, lg = lane >> 4;
  const int m0 = by * 128;
  const int n0 = bx * 128;
  const int wr = (wave >> 1) * 64, wc = (wave & 1) * 64;

  f32x4 acc[4][4] = {};

  const int idx0 = tid, idx1 = tid + 256;
  const char* gA0 = (const char*)(A + (size_t)(m0 + (idx0 >> 2)) * Kk) + (idx0 & 3) * 16;
  const char* gA1 = (const char*)(A + (size_t)(m0 + (idx1 >> 2)) * Kk) + (idx1 & 3) * 16;
  const char* gB0 = (const char*)(Bt + (size_t)(n0 + (idx0 >> 2)) * Kk) + (idx0 & 3) * 16;
  const char* gB1 = (const char*)(Bt + (size_t)(n0 + (idx1 >> 2)) * Kk) + (idx1 & 3) * 16;
  bf16* lA0 = &As[(wave * 64) * 8];
  bf16* lA1 = &As[(256 + wave * 64) * 8];
  bf16* lB0 = &Bs[(wave * 64) * 8];
  bf16* lB1 = &Bs[(256 + wave * 64) * 8];

  const int ksteps = Kk >> 5;
  for (int kt = 0; kt < ksteps; ++kt) {
    load_lds16(gA0, lA0); load_lds16(gA1, lA1);
    load_lds16(gB0, lB0); load_lds16(gB1, lB1);
    gA0 += 64; gA1 += 64; gB0 += 64; gB1 += 64;
    __syncthreads();
    bf16x8 af[4], bfr[4];
#pragma unroll
    for (int i = 0; i < 4; ++i)
      af[i] = *(const bf16x8*)&As[(wr + i * 16 + lr) * 32 + lg * 8];
#pragma unroll
    for (int j = 0; j < 4; ++j)
      bfr[j] = *(const bf16x8*)&Bs[(wc + j * 16 + lr) * 32 + lg * 8];
#pragma unroll
    for (int i = 0; i < 4; ++i)
#pragma unroll
      for (int j = 0; j < 4; ++j)
        acc[i][j] = MFMA16(af[i], bfr[j], acc[i][j]);
    __syncthreads();
  }

#pragma unroll
  for (int i = 0; i < 4; ++i) {
#pragma unroll
    for (int j = 0; j < 4; ++j) {
#pragma unroll
      for (int r = 0; r < 4; ++r) {
        const int row = m0 + wr + i * 16 + lg * 4 + r;
        const int col = n0 + wc + j * 16 + lr;
        float val = acc[i][j][r];
        if (EPI == 0) {
          const int which = col >> 10, hc = col & 1023;
          const float* bs = (which == 0) ? bias0 : (which == 1) ? bias1 : bias2;
          bf16* dst = (which == 0) ? q_out : (which == 1) ? k_out : v_out;
          val += bs[hc];
          const int b = row >> 11, s = row & 2047;
          const int h = hc >> 6, hd = hc & 63;
          dst[(((size_t)b * 16 + h) * 2048 + s) * 64 + hd] = (bf16)val;
        } else {
          val += bias0[col];
          outb[(size_t)row * Nn + col] = (bf16)(val > 0.f ? val : 0.f);
        }
      }
    }
  }
}

// -------- GEMM 64x64 tile (for N=1024 shapes): + bias + resid -> fp32 -------
// grid = (M/64)*(N/64) 1D, XCD-swizzled. 4 waves, each 32x32 output.
__global__ __launch_bounds__(256) void gemm64(
    const bf16* __restrict__ A, const bf16* __restrict__ Bt, int Kk, int Nn, int nbx,
    const float* __restrict__ bias0, const bf16* __restrict__ resid,
    float* __restrict__ outf) {
  __shared__ __align__(16) bf16 As[64 * 32];
  __shared__ __align__(16) bf16 Bs[64 * 32];
  const int cpx = gridDim.x >> 3;
  const int wg = (blockIdx.x & 7) * cpx + (blockIdx.x >> 3);
  const int bx = wg % nbx, by = wg / nbx;
  const int tid = threadIdx.x;
  const int lane = tid & 63;
  const int wave = tid >> 6;
  const int lr = lane & 15, lg = lane >> 4;
  const int m0 = by * 64, n0 = bx * 64;
  const int wr = (wave >> 1) * 32, wc = (wave & 1) * 32;

  f32x4 acc[2][2] = {};

  const char* gA = (const char*)(A + (size_t)(m0 + (tid >> 2)) * Kk) + (tid & 3) * 16;
  const char* gB = (const char*)(Bt + (size_t)(n0 + (tid >> 2)) * Kk) + (tid & 3) * 16;
  bf16* lA = &As[wave * 512];
  bf16* lB = &Bs[wave * 512];

  const int ksteps = Kk >> 5;
  for (int kt = 0; kt < ksteps; ++kt) {
    load_lds16(gA, lA);
    load_lds16(gB, lB);
    gA += 64; gB += 64;
    __syncthreads();
    bf16x8 af[2], bfr[2];
#pragma unroll
    for (int i = 0; i < 2; ++i)
      af[i] = *(const bf16x8*)&As[(wr + i * 16 + lr) * 32 + lg * 8];
#pragma unroll
    for (int j = 0; j < 2; ++j)
      bfr[j] = *(const bf16x8*)&Bs[(wc + j * 16 + lr) * 32 + lg * 8];
#pragma unroll
    for (int i = 0; i < 2; ++i)
#pragma unroll
      for (int j = 0; j < 2; ++j)
        acc[i][j] = MFMA16(af[i], bfr[j], acc[i][j]);
    __syncthreads();
  }

#pragma unroll
  for (int i = 0; i < 2; ++i)
#pragma unroll
    for (int j = 0; j < 2; ++j)
#pragma unroll
      for (int r = 0; r < 4; ++r) {
        const int row = m0 + wr + i * 16 + lg * 4 + r;
        const int col = n0 + wc + j * 16 + lr;
        const float val = acc[i][j][r] + bias0[col] + (float)resid[(size_t)row * Nn + col];
        outf[(size_t)row * Nn + col] = val;
      }
}

// ------------------------- flash attention (per b,h) ------------------------
// grid: (S/64, B*H). block: 256 = 4 waves; wave w owns q-rows [64*bx + 16w, +16)
// K in [bh][s][64]; V^T in [bh][64][s].
// Swapped QK^T (S^T in lanes: q=lr, keys=lg*4+r per ks-tile), log2-domain
// online softmax with defer-max, XOR-swizzled LDS (col8 ^= row&7).
// NOTE: chunk loop MUST be unrolled by 2 so kr[pp]/vr[pp] indices are
// compile-time constants (rule #20: runtime-indexed ext_vector arrays go to
// scratch -> 7x slowdown, seen in round 3).
__global__ __launch_bounds__(256) void attn_kernel(const bf16* __restrict__ q,
                                                   const bf16* __restrict__ k,
                                                   const bf16* __restrict__ vt,
                                                   bf16* __restrict__ ctxo) {
  __shared__ __align__(16) bf16 Kl[64][64];
  __shared__ __align__(16) bf16 Vt[64][64];   // rows = hd, cols = key
  __shared__ __align__(16) bf16 Pl[4][16][64];
  const int tid = threadIdx.x;
  const int lane = tid & 63, w = tid >> 6;
  const int lr = lane & 15, lg = lane >> 4;
  const int swz = lr & 7;
  const int bh = blockIdx.y;
  const int q0 = blockIdx.x * 64;

  // Q fragment (B-operand rows = q), pre-scaled by (1/sqrt(64))*log2(e)
  const bf16* qp = q + ((size_t)bh * 2048 + q0 + w * 16) * 64;
  bf16x8 qf0 = *(const bf16x8*)&qp[lr * 64 + lg * 8];
  bf16x8 qf1 = *(const bf16x8*)&qp[lr * 64 + lg * 8 + 32];
  const float qs = 0.18033688011112042f;
#pragma unroll
  for (int j = 0; j < 8; ++j) {
    qf0[j] = (bf16)((float)qf0[j] * qs);
    qf1[j] = (bf16)((float)qf1[j] * qs);
  }
  bf16x8 ones8;
#pragma unroll
  for (int j = 0; j < 8; ++j) ones8[j] = (bf16)1.0f;

  const bf16* kbase = k + (size_t)bh * 2048 * 64;
  const bf16* vtb = vt + (size_t)bh * 64 * 2048;

  const int sr0 = tid >> 3, sr1 = sr0 + 32;       // staging rows
  const int c0 = (tid & 7) * 8;                   // unswizzled col
  const int cs0 = c0 ^ ((sr0 & 7) << 3);          // swizzled col
  const int cs1 = c0 ^ ((sr1 & 7) << 3);

  f32x4 acc[4] = {};
  f32x4 accl = {};                                // P row-sums via ones-MFMA
  float mq = -1e30f;                              // per-lane running max (q = lr)

  bf16x8 kr[2][2], vr[2][2];
  kr[0][0] = *(const bf16x8*)&kbase[(size_t)sr0 * 64 + c0];
  kr[0][1] = *(const bf16x8*)&kbase[(size_t)sr1 * 64 + c0];
  vr[0][0] = *(const bf16x8*)&vtb[(size_t)sr0 * 2048 + c0];
  vr[0][1] = *(const bf16x8*)&vtb[(size_t)sr1 * 2048 + c0];

#pragma unroll 2
  for (int c = 0; c < 32; ++c) {
    const int pp = c & 1;
    *(bf16x8*)&Kl[sr0][cs0] = kr[pp][0];
    *(bf16x8*)&Kl[sr1][cs1] = kr[pp][1];
    *(bf16x8*)&Vt[sr0][cs0] = vr[pp][0];
    *(bf16x8*)&Vt[sr1][cs1] = vr[pp][1];
    if (c + 1 < 32) {                              // next-chunk loads, pre-barrier
      const int key0n = (c + 1) * 64;
      kr[pp ^ 1][0] = *(const bf16x8*)&kbase[(size_t)(key0n + sr0) * 64 + c0];
      kr[pp ^ 1][1] = *(const bf16x8*)&kbase[(size_t)(key0n + sr1) * 64 + c0];
      vr[pp ^ 1][0] = *(const bf16x8*)&vtb[(size_t)sr0 * 2048 + key0n + c0];
      vr[pp ^ 1][1] = *(const bf16x8*)&vtb[(size_t)sr1 * 2048 + key0n + c0];
    }
    __syncthreads();

    // --- swapped QK^T: st[ks][r] = S*log2e [q=lr][key = ks*16 + lg*4 + r] ---
    f32x4 st[4];
    __builtin_amdgcn_s_setprio(1);
#pragma unroll
    for (int ks = 0; ks < 4; ++ks) {
      const bf16x8 kf0 = *(const bf16x8*)&Kl[ks * 16 + lr][(lg ^ swz) << 3];
      const bf16x8 kf1 = *(const bf16x8*)&Kl[ks * 16 + lr][((lg + 4) ^ swz) << 3];
      f32x4 sa = {};
      sa = MFMA16(kf0, qf0, sa);
      sa = MFMA16(kf1, qf1, sa);
      st[ks] = sa;
    }
    __builtin_amdgcn_s_setprio(0);

    // --- in-lane online softmax (log2 domain) ---
    float mx = st[0][0];
#pragma unroll
    for (int ks = 0; ks < 4; ++ks)
#pragma unroll
      for (int r = 0; r < 4; ++r) mx = fmaxf(mx, st[ks][r]);
    mx = fmaxf(mx, __shfl_xor(mx, 16));
    mx = fmaxf(mx, __shfl_xor(mx, 32));
    if (!__all(mx - mq <= 8.0f)) {                 // defer-max (T13)
      const float resc = exp2f(mq - mx);
      mq = mx;
      float rq[4];
#pragma unroll
      for (int r = 0; r < 4; ++r) rq[r] = __shfl(resc, lg * 4 + r);
#pragma unroll
      for (int r = 0; r < 4; ++r) {
        accl[r] *= rq[r];
#pragma unroll
        for (int jn = 0; jn < 4; ++jn) acc[jn][r] *= rq[r];
      }
    }
#pragma unroll
    for (int ks = 0; ks < 4; ++ks) {               // P pack + vectorized store
      bf16x4 pk;
#pragma unroll
      for (int r = 0; r < 4; ++r) pk[r] = (bf16)exp2f(st[ks][r] - mq);
      const int col = (((ks * 2 + (lg >> 1)) ^ swz) << 3) + ((lg & 1) << 2);
      *(bf16x4*)&Pl[w][lr][col] = pk;
    }

    // --- PV + denominators ---
    const bf16x8 pf0 = *(const bf16x8*)&Pl[w][lr][(lg ^ swz) << 3];
    const bf16x8 pf1 = *(const bf16x8*)&Pl[w][lr][((lg + 4) ^ swz) << 3];
    __builtin_amdgcn_s_setprio(1);
#pragma unroll
    for (int jn = 0; jn < 4; ++jn) {
      const bf16x8 vf0 = *(const bf16x8*)&Vt[jn * 16 + lr][(lg ^ swz) << 3];
      const bf16x8 vf1 = *(const bf16x8*)&Vt[jn * 16 + lr][((lg + 4) ^ swz) << 3];
      acc[jn] = MFMA16(pf0, vf0, acc[jn]);
      acc[jn] = MFMA16(pf1, vf1, acc[jn]);
    }
    accl = MFMA16(pf0, ones8, accl);
    accl = MFMA16(pf1, ones8, accl);
    __builtin_amdgcn_s_setprio(0);
    __syncthreads();
  }

  const int bb = bh >> 4, hh = bh & 15;
#pragma unroll
  for (int r = 0; r < 4; ++r) {
    const float inv = 1.f / accl[r];
    const size_t rowg = (size_t)bb * 2048 + q0 + w * 16 + lg * 4 + r;
#pragma unroll
    for (int jn = 0; jn < 4; ++jn)
      ctxo[rowg * 1024 + hh * 64 + jn * 16 + lr] = (bf16)(acc[jn][r] * inv);
  }
}

// ------------------------------ LayerNorm -----------------------------------
__global__ __launch_bounds__(256) void ln_kernel(const float* __restrict__ y,
                                                 const float* __restrict__ g,
                                                 const float* __restrict__ be,
                                                 bf16* __restrict__ xo) {
  const int row = blockIdx.x, tid = threadIdx.x;
  const float4 v = ((const float4*)(y + (size_t)row * 1024))[tid];
  float s = v.x + v.y + v.z + v.w;
  float s2 = v.x * v.x + v.y * v.y + v.z * v.z + v.w * v.w;
#pragma unroll
  for (int o = 32; o > 0; o >>= 1) { s += __shfl_down(s, o); s2 += __shfl_down(s2, o); }
  __shared__ float red[8];
  if ((tid & 63) == 0) { red[tid >> 6] = s; red[4 + (tid >> 6)] = s2; }
  __syncthreads();
  s = red[0] + red[1] + red[2] + red[3];
  s2 = red[4] + red[5] + red[6] + red[7];
  const float mean = s * (1.f / 1024.f);
  const float var = s2 * (1.f / 1024.f) - mean * mean;
  const float rstd = rsqrtf(var + 1e-5f);
  const float4 gv = ((const float4*)g)[tid];
  const float4 bv = ((const float4*)be)[tid];
  bf16x4 o4;
  o4[0] = (bf16)((v.x - mean) * rstd * gv.x + bv.x);
  o4[1] = (bf16)((v.y - mean) * rstd * gv.y + bv.y);
  o4[2] = (bf16)((v.z - mean) * rstd * gv.z + bv.z);
  o4[3] = (bf16)((v.w - mean) * rstd * gv.w + bv.w);
  *(bf16x4*)&xo[(size_t)row * 1024 + tid * 4] = o4;
}

// ------------------------------ bf16 -> fp32 --------------------------------
__global__ __launch_bounds__(256) void to_f32_kernel(const bf16* __restrict__ x,
                                                     float* __restrict__ o) {
  const size_t i = ((size_t)blockIdx.x * 256 + threadIdx.x) * 4;
  const bf16x4 v = *(const bf16x4*)&x[i];
  float4 f;
  f.x = (float)v[0]; f.y = (float)v[1]; f.z = (float)v[2]; f.w = (float)v[3];
  *(float4*)&o[i] = f;
}

// ----------------------------------------------------------------------------
extern "C" void kernel_launch(void* const* d_in, const int* in_sizes, int n_in,
                              void* d_out, int out_size, void* d_ws, size_t ws_size,
                              hipStream_t stream) {
  const int* tokens = (const int*)d_in[0];
  const float* emb = (const float*)d_in[2];
  const float* Wq = (const float*)d_in[3];
  const float* bq = (const float*)d_in[4];
  const float* Wk = (const float*)d_in[5];
  const float* bk = (const float*)d_in[6];
  const float* Wv = (const float*)d_in[7];
  const float* bv = (const float*)d_in[8];
  const float* Wo = (const float*)d_in[9];
  const float* bo = (const float*)d_in[10];
  const float* W1 = (const float*)d_in[11];
  const float* b1 = (const float*)d_in[12];
  const float* W2 = (const float*)d_in[13];
  const float* b2 = (const float*)d_in[14];
  const float* g1 = (const float*)d_in[15];
  const float* be1 = (const float*)d_in[16];
  const float* g2 = (const float*)d_in[17];
  const float* be2 = (const float*)d_in[18];

  char* p = (char*)d_ws;
  auto carve = [&](size_t bytes) { char* r = p; p += (bytes + 255) & ~(size_t)255; return r; };
  bf16* wt_qkv = (bf16*)carve((size_t)3072 * 1024 * 2);
  bf16* wt_o   = (bf16*)carve((size_t)1024 * 1024 * 2);
  bf16* wt_1   = (bf16*)carve((size_t)4096 * 1024 * 2);
  bf16* wt_2   = (bf16*)carve((size_t)1024 * 4096 * 2);
  bf16* xb     = (bf16*)carve((size_t)4096 * 1024 * 2);
  bf16* qb     = (bf16*)carve((size_t)4096 * 1024 * 2);
  bf16* kb     = (bf16*)carve((size_t)4096 * 1024 * 2);
  bf16* vb     = (bf16*)carve((size_t)4096 * 1024 * 2);
  bf16* vtb    = (bf16*)carve((size_t)4096 * 1024 * 2);
  bf16* ctxb   = (bf16*)carve((size_t)4096 * 1024 * 2);
  float* yb    = (float*)carve((size_t)4096 * 1024 * 4);
  bf16* hb     = (bf16*)carve((size_t)4096 * 4096 * 2);

  embed_kernel<<<4096, 256, 0, stream>>>(tokens, emb, xb);

  for (int l = 0; l < 6; ++l) {
    TArgs ta;
    ta.j[0] = { Wq + (size_t)l * 1024 * 1024, wt_qkv,                  1024, 1024, 0 };
    ta.j[1] = { Wk + (size_t)l * 1024 * 1024, wt_qkv + 1024 * 1024,    1024, 1024, 1024 };
    ta.j[2] = { Wv + (size_t)l * 1024 * 1024, wt_qkv + 2 * 1024 * 1024,1024, 1024, 2048 };
    ta.j[3] = { Wo + (size_t)l * 1024 * 1024, wt_o,                    1024, 1024, 3072 };
    ta.j[4] = { W1 + (size_t)l * 1024 * 4096, wt_1,                    1024, 4096, 4096 };
    ta.j[5] = { W2 + (size_t)l * 4096 * 1024, wt_2,                    4096, 1024, 8192 };
    wtrans_kernel<<<12288, 256, 0, stream>>>(ta);

    gemm_bt<0><<<768, 256, 0, stream>>>(xb, wt_qkv, 1024, 3072, 24,
        bq + (size_t)l * 1024, bk + (size_t)l * 1024, bv + (size_t)l * 1024,
        nullptr, qb, kb, vb);

    vtrans_kernel<<<dim3(32, 32), 256, 0, stream>>>(vb, vtb);

    attn_kernel<<<dim3(32, 32), 256, 0, stream>>>(qb, kb, vtb, ctxb);

    gemm64<<<1024, 256, 0, stream>>>(ctxb, wt_o, 1024, 1024, 16,
        bo + (size_t)l * 1024, xb, yb);

    ln_kernel<<<4096, 256, 0, stream>>>(yb, g1 + (size_t)l * 1024, be1 + (size_t)l * 1024, xb);

    gemm_bt<2><<<1024, 256, 0, stream>>>(xb, wt_1, 1024, 4096, 32,
        b1 + (size_t)l * 4096, nullptr, nullptr, hb,
        nullptr, nullptr, nullptr);

    gemm64<<<1024, 256, 0, stream>>>(hb, wt_2, 4096, 1024, 16,
        b2 + (size_t)l * 1024, xb, yb);

    ln_kernel<<<4096, 256, 0, stream>>>(yb, g2 + (size_t)l * 1024, be2 + (size_t)l * 1024, xb);
  }

  to_f32_kernel<<<4096, 256, 0, stream>>>(xb, (float*)d_out);
}

// Round 5
// 1723.067 us; speedup vs baseline: 3.4823x; 1.0254x over previous
//
#include <hip/hip_runtime.h>
#include <hip/hip_bf16.h>
#include <cstdint>
#include <cstddef>

// ---------------------------------------------------------------------------
// Transformer encoder, 6 layers: B=2,S=2048,D=1024,H=16,HD=64,F=4096.
// bf16 MFMA GEMMs (128^2 m97 structure; split-K for N=1024 shapes),
// flash attention (swapped QK^T, in-lane softmax, T2 swizzle), fp32 LN.
// ---------------------------------------------------------------------------

typedef __bf16 bf16;
typedef __bf16 bf16x2 __attribute__((ext_vector_type(2)));
typedef __bf16 bf16x4 __attribute__((ext_vector_type(4)));
typedef __bf16 bf16x8 __attribute__((ext_vector_type(8)));
typedef float  f32x4  __attribute__((ext_vector_type(4)));

#define MFMA16(a, b, c) __builtin_amdgcn_mfma_f32_16x16x32_bf16((a), (b), (c), 0, 0, 0)

static __device__ __forceinline__ void load_lds16(const void* g, void* l) {
  __builtin_amdgcn_global_load_lds((const __attribute__((address_space(1))) void*)g,
                                   (__attribute__((address_space(3))) void*)l, 16, 0, 0);
}

// ---------------- embedding + positional encoding -> bf16 x ----------------
__global__ __launch_bounds__(256) void embed_kernel(const int* __restrict__ tok,
                                                    const float* __restrict__ emb,
                                                    bf16* __restrict__ xo) {
  const int row = blockIdx.x;          // b*2048 + s
  const int s = row & 2047;
  const int t = tok[row];
  const int d0 = threadIdx.x * 4;
  const float4 e = *(const float4*)&emb[(size_t)t * 1024 + d0];
  const float* ef = (const float*)&e;
  bf16x4 o4;
#pragma unroll
  for (int j = 0; j < 4; ++j) {
    const int d = d0 + j;
    const float div = __expf(-(float)(d & ~1) * 0.00899447301950864f); // ln(1e4)/1024
    const float arg = (float)s * div;
    const float pe = (d & 1) ? cosf(arg) : sinf(arg);
    o4[j] = (bf16)(ef[j] + pe);
  }
  *(bf16x4*)&xo[(size_t)row * 1024 + d0] = o4;
}

// ------------- weight transpose: fp32 [K][N] -> bf16 [N][K], batched --------
struct TJob { const float* src; bf16* dst; int K; int N; int t0; };
struct TArgs { TJob j[6]; };

__global__ __launch_bounds__(256) void wtrans_kernel(TArgs a) {
  __shared__ float t[32][33];
  const int blk = blockIdx.x;
  const float* src = a.j[0].src; bf16* dst = a.j[0].dst;
  int K = a.j[0].K, N = a.j[0].N, t0 = a.j[0].t0;
#pragma unroll
  for (int q = 1; q < 6; ++q)
    if (blk >= a.j[q].t0) { src = a.j[q].src; dst = a.j[q].dst; K = a.j[q].K; N = a.j[q].N; t0 = a.j[q].t0; }
  const int tj = blk - t0;
  const int tilesK = K >> 5;
  const int tk = (tj % tilesK) << 5;
  const int tn = (tj / tilesK) << 5;
  const int lx = threadIdx.x & 31, ly = threadIdx.x >> 5;
#pragma unroll
  for (int i = 0; i < 4; ++i)
    t[ly + 8 * i][lx] = src[(size_t)(tk + ly + 8 * i) * N + tn + lx];
  __syncthreads();
#pragma unroll
  for (int i = 0; i < 4; ++i)
    dst[(size_t)(tn + ly + 8 * i) * K + tk + lx] = (bf16)t[lx][ly + 8 * i];
}

// -------- V transpose per layer: [bh][s][64] bf16 -> [bh][64][s] bf16 -------
__global__ __launch_bounds__(256) void vtrans_kernel(const bf16* __restrict__ v,
                                                     bf16* __restrict__ vt) {
  __shared__ bf16 t[64][72];
  const int bh = blockIdx.y;
  const int s0 = blockIdx.x * 64;
  const int tid = threadIdx.x;
#pragma unroll
  for (int it = 0; it < 2; ++it) {
    const int idx = tid + it * 256;
    const int sr = idx >> 3, h8 = (idx & 7) * 8;
    *(bf16x8*)&t[sr][h8] = *(const bf16x8*)&v[((size_t)bh * 2048 + s0 + sr) * 64 + h8];
  }
  __syncthreads();
#pragma unroll
  for (int it = 0; it < 2; ++it) {
    const int idx = tid + it * 256;
    const int hd = idx >> 3, s8 = (idx & 7) * 8;
    bf16x8 o;
#pragma unroll
    for (int j = 0; j < 8; ++j) o[j] = t[s8 + j][hd];
    *(bf16x8*)&vt[((size_t)bh * 64 + hd) * 2048 + s0 + s8] = o;
  }
}

// ---------------- GEMM: C[M,N] = A[M,K]bf16 * Bt[N,K]bf16, 128x128 ---------
// 1D grid with XCD swizzle (grid % 8 == 0). nbx = N/128.
// EPI 0: + per-segment bias, scatter to q/k/v [B,H,S,64]
// EPI 2: + bias, ReLU -> bf16 out
template <int EPI>
__global__ __launch_bounds__(256) void gemm_bt(
    const bf16* __restrict__ A, const bf16* __restrict__ Bt, int Kk, int Nn, int nbx,
    const float* __restrict__ bias0, const float* __restrict__ bias1,
    const float* __restrict__ bias2, bf16* __restrict__ outb,
    bf16* __restrict__ q_out, bf16* __restrict__ k_out, bf16* __restrict__ v_out) {
  __shared__ __align__(16) bf16 As[128 * 32];
  __shared__ __align__(16) bf16 Bs[128 * 32];
  const int cpx = gridDim.x >> 3;
  const int wg = (blockIdx.x & 7) * cpx + (blockIdx.x >> 3);
  const int bx = wg % nbx, by = wg / nbx;
  const int tid = threadIdx.x;
  const int lane = tid & 63;
  const int wave = tid >> 6;
  const int lr = lane & 15, lg = lane >> 4;
  const int m0 = by * 128;
  const int n0 = bx * 128;
  const int wr = (wave >> 1) * 64, wc = (wave & 1) * 64;

  f32x4 acc[4][4] = {};

  const int idx0 = tid, idx1 = tid + 256;
  const char* gA0 = (const char*)(A + (size_t)(m0 + (idx0 >> 2)) * Kk) + (idx0 & 3) * 16;
  const char* gA1 = (const char*)(A + (size_t)(m0 + (idx1 >> 2)) * Kk) + (idx1 & 3) * 16;
  const char* gB0 = (const char*)(Bt + (size_t)(n0 + (idx0 >> 2)) * Kk) + (idx0 & 3) * 16;
  const char* gB1 = (const char*)(Bt + (size_t)(n0 + (idx1 >> 2)) * Kk) + (idx1 & 3) * 16;
  bf16* lA0 = &As[(wave * 64) * 8];
  bf16* lA1 = &As[(256 + wave * 64) * 8];
  bf16* lB0 = &Bs[(wave * 64) * 8];
  bf16* lB1 = &Bs[(256 + wave * 64) * 8];

  const int ksteps = Kk >> 5;
  for (int kt = 0; kt < ksteps; ++kt) {
    load_lds16(gA0, lA0); load_lds16(gA1, lA1);
    load_lds16(gB0, lB0); load_lds16(gB1, lB1);
    gA0 += 64; gA1 += 64; gB0 += 64; gB1 += 64;
    __syncthreads();
    bf16x8 af[4], bfr[4];
#pragma unroll
    for (int i = 0; i < 4; ++i)
      af[i] = *(const bf16x8*)&As[(wr + i * 16 + lr) * 32 + lg * 8];
#pragma unroll
    for (int j = 0; j < 4; ++j)
      bfr[j] = *(const bf16x8*)&Bs[(wc + j * 16 + lr) * 32 + lg * 8];
#pragma unroll
    for (int i = 0; i < 4; ++i)
#pragma unroll
      for (int j = 0; j < 4; ++j)
        acc[i][j] = MFMA16(af[i], bfr[j], acc[i][j]);
    __syncthreads();
  }

#pragma unroll
  for (int i = 0; i < 4; ++i) {
#pragma unroll
    for (int j = 0; j < 4; ++j) {
#pragma unroll
      for (int r = 0; r < 4; ++r) {
        const int row = m0 + wr + i * 16 + lg * 4 + r;
        const int col = n0 + wc + j * 16 + lr;
        float val = acc[i][j][r];
        if (EPI == 0) {
          const int which = col >> 10, hc = col & 1023;
          const float* bs = (which == 0) ? bias0 : (which == 1) ? bias1 : bias2;
          bf16* dst = (which == 0) ? q_out : (which == 1) ? k_out : v_out;
          val += bs[hc];
          const int b = row >> 11, s = row & 2047;
          const int h = hc >> 6, hd = hc & 63;
          dst[(((size_t)b * 16 + h) * 2048 + s) * 64 + hd] = (bf16)val;
        } else {
          val += bias0[col];
          outb[(size_t)row * Nn + col] = (bf16)(val > 0.f ? val : 0.f);
        }
      }
    }
  }
}

// -------- split-K GEMM, 128x128 tile, N=1024: partial fp32, no bias --------
// grid: (nbx*nby [XCD-swizzled], KSLICES). Kstride = full K (row stride),
// Kloop = K per slice. pout slice s at pout + s*4096*1024.
__global__ __launch_bounds__(256) void gemm_sk(
    const bf16* __restrict__ A, const bf16* __restrict__ Bt,
    int Kstride, int Kloop, int nbx, float* __restrict__ pout) {
  __shared__ __align__(16) bf16 As[128 * 32];
  __shared__ __align__(16) bf16 Bs[128 * 32];
  const int bz = blockIdx.y;
  const bf16* Ab = A + (size_t)bz * Kloop;
  const bf16* Bb = Bt + (size_t)bz * Kloop;
  float* pb = pout + (size_t)bz * 4096 * 1024;
  const int cpx = gridDim.x >> 3;
  const int wg = (blockIdx.x & 7) * cpx + (blockIdx.x >> 3);
  const int bx = wg % nbx, by = wg / nbx;
  const int tid = threadIdx.x;
  const int lane = tid & 63;
  const int wave = tid >> 6;
  const int lr = lane & 15, lg = lane >> 4;
  const int m0 = by * 128;
  const int n0 = bx * 128;
  const int wr = (wave >> 1) * 64, wc = (wave & 1) * 64;

  f32x4 acc[4][4] = {};

  const int idx0 = tid, idx1 = tid + 256;
  const char* gA0 = (const char*)(Ab + (size_t)(m0 + (idx0 >> 2)) * Kstride) + (idx0 & 3) * 16;
  const char* gA1 = (const char*)(Ab + (size_t)(m0 + (idx1 >> 2)) * Kstride) + (idx1 & 3) * 16;
  const char* gB0 = (const char*)(Bb + (size_t)(n0 + (idx0 >> 2)) * Kstride) + (idx0 & 3) * 16;
  const char* gB1 = (const char*)(Bb + (size_t)(n0 + (idx1 >> 2)) * Kstride) + (idx1 & 3) * 16;
  bf16* lA0 = &As[(wave * 64) * 8];
  bf16* lA1 = &As[(256 + wave * 64) * 8];
  bf16* lB0 = &Bs[(wave * 64) * 8];
  bf16* lB1 = &Bs[(256 + wave * 64) * 8];

  const int ksteps = Kloop >> 5;
  for (int kt = 0; kt < ksteps; ++kt) {
    load_lds16(gA0, lA0); load_lds16(gA1, lA1);
    load_lds16(gB0, lB0); load_lds16(gB1, lB1);
    gA0 += 64; gA1 += 64; gB0 += 64; gB1 += 64;
    __syncthreads();
    bf16x8 af[4], bfr[4];
#pragma unroll
    for (int i = 0; i < 4; ++i)
      af[i] = *(const bf16x8*)&As[(wr + i * 16 + lr) * 32 + lg * 8];
#pragma unroll
    for (int j = 0; j < 4; ++j)
      bfr[j] = *(const bf16x8*)&Bs[(wc + j * 16 + lr) * 32 + lg * 8];
#pragma unroll
    for (int i = 0; i < 4; ++i)
#pragma unroll
      for (int j = 0; j < 4; ++j)
        acc[i][j] = MFMA16(af[i], bfr[j], acc[i][j]);
    __syncthreads();
  }

#pragma unroll
  for (int i = 0; i < 4; ++i)
#pragma unroll
    for (int j = 0; j < 4; ++j)
#pragma unroll
      for (int r = 0; r < 4; ++r) {
        const int row = m0 + wr + i * 16 + lg * 4 + r;
        const int col = n0 + wc + j * 16 + lr;
        pb[(size_t)row * 1024 + col] = acc[i][j][r];
      }
}

// ------------------------- flash attention (per b,h) ------------------------
// grid: (S/64, B*H). block: 256 = 4 waves; wave w owns q-rows [64*bx + 16w, +16)
// K in [bh][s][64]; V^T in [bh][64][s].
// Swapped QK^T (S^T in lanes: q=lr, keys=lg*4+r per ks-tile), log2-domain
// online softmax with defer-max, XOR-swizzled LDS (col8 ^= row&7).
// NOTE: chunk loop MUST be unrolled by 2 so kr[pp]/vr[pp] indices are
// compile-time constants (rule #20: runtime-indexed ext_vector arrays go to
// scratch -> 7x slowdown, seen in round 3).
__global__ __launch_bounds__(256) void attn_kernel(const bf16* __restrict__ q,
                                                   const bf16* __restrict__ k,
                                                   const bf16* __restrict__ vt,
                                                   bf16* __restrict__ ctxo) {
  __shared__ __align__(16) bf16 Kl[64][64];
  __shared__ __align__(16) bf16 Vt[64][64];   // rows = hd, cols = key
  __shared__ __align__(16) bf16 Pl[4][16][64];
  const int tid = threadIdx.x;
  const int lane = tid & 63, w = tid >> 6;
  const int lr = lane & 15, lg = lane >> 4;
  const int swz = lr & 7;
  const int bh = blockIdx.y;
  const int q0 = blockIdx.x * 64;

  // Q fragment (B-operand rows = q), pre-scaled by (1/sqrt(64))*log2(e)
  const bf16* qp = q + ((size_t)bh * 2048 + q0 + w * 16) * 64;
  bf16x8 qf0 = *(const bf16x8*)&qp[lr * 64 + lg * 8];
  bf16x8 qf1 = *(const bf16x8*)&qp[lr * 64 + lg * 8 + 32];
  const float qs = 0.18033688011112042f;
#pragma unroll
  for (int j = 0; j < 8; ++j) {
    qf0[j] = (bf16)((float)qf0[j] * qs);
    qf1[j] = (bf16)((float)qf1[j] * qs);
  }
  bf16x8 ones8;
#pragma unroll
  for (int j = 0; j < 8; ++j) ones8[j] = (bf16)1.0f;

  const bf16* kbase = k + (size_t)bh * 2048 * 64;
  const bf16* vtb = vt + (size_t)bh * 64 * 2048;

  const int sr0 = tid >> 3, sr1 = sr0 + 32;       // staging rows
  const int c0 = (tid & 7) * 8;                   // unswizzled col
  const int cs0 = c0 ^ ((sr0 & 7) << 3);          // swizzled col
  const int cs1 = c0 ^ ((sr1 & 7) << 3);

  f32x4 acc[4] = {};
  f32x4 accl = {};                                // P row-sums via ones-MFMA
  float mq = -1e30f;                              // per-lane running max (q = lr)

  bf16x8 kr[2][2], vr[2][2];
  kr[0][0] = *(const bf16x8*)&kbase[(size_t)sr0 * 64 + c0];
  kr[0][1] = *(const bf16x8*)&kbase[(size_t)sr1 * 64 + c0];
  vr[0][0] = *(const bf16x8*)&vtb[(size_t)sr0 * 2048 + c0];
  vr[0][1] = *(const bf16x8*)&vtb[(size_t)sr1 * 2048 + c0];

#pragma unroll 2
  for (int c = 0; c < 32; ++c) {
    const int pp = c & 1;
    *(bf16x8*)&Kl[sr0][cs0] = kr[pp][0];
    *(bf16x8*)&Kl[sr1][cs1] = kr[pp][1];
    *(bf16x8*)&Vt[sr0][cs0] = vr[pp][0];
    *(bf16x8*)&Vt[sr1][cs1] = vr[pp][1];
    if (c + 1 < 32) {                              // next-chunk loads, pre-barrier
      const int key0n = (c + 1) * 64;
      kr[pp ^ 1][0] = *(const bf16x8*)&kbase[(size_t)(key0n + sr0) * 64 + c0];
      kr[pp ^ 1][1] = *(const bf16x8*)&kbase[(size_t)(key0n + sr1) * 64 + c0];
      vr[pp ^ 1][0] = *(const bf16x8*)&vtb[(size_t)sr0 * 2048 + key0n + c0];
      vr[pp ^ 1][1] = *(const bf16x8*)&vtb[(size_t)sr1 * 2048 + key0n + c0];
    }
    __syncthreads();

    // --- swapped QK^T: st[ks][r] = S*log2e [q=lr][key = ks*16 + lg*4 + r] ---
    f32x4 st[4];
    __builtin_amdgcn_s_setprio(1);
#pragma unroll
    for (int ks = 0; ks < 4; ++ks) {
      const bf16x8 kf0 = *(const bf16x8*)&Kl[ks * 16 + lr][(lg ^ swz) << 3];
      const bf16x8 kf1 = *(const bf16x8*)&Kl[ks * 16 + lr][((lg + 4) ^ swz) << 3];
      f32x4 sa = {};
      sa = MFMA16(kf0, qf0, sa);
      sa = MFMA16(kf1, qf1, sa);
      st[ks] = sa;
    }
    __builtin_amdgcn_s_setprio(0);

    // --- in-lane online softmax (log2 domain) ---
    float mx = st[0][0];
#pragma unroll
    for (int ks = 0; ks < 4; ++ks)
#pragma unroll
      for (int r = 0; r < 4; ++r) mx = fmaxf(mx, st[ks][r]);
    mx = fmaxf(mx, __shfl_xor(mx, 16));
    mx = fmaxf(mx, __shfl_xor(mx, 32));
    if (!__all(mx - mq <= 8.0f)) {                 // defer-max (T13)
      const float resc = exp2f(mq - mx);
      mq = mx;
      float rq[4];
#pragma unroll
      for (int r = 0; r < 4; ++r) rq[r] = __shfl(resc, lg * 4 + r);
#pragma unroll
      for (int r = 0; r < 4; ++r) {
        accl[r] *= rq[r];
#pragma unroll
        for (int jn = 0; jn < 4; ++jn) acc[jn][r] *= rq[r];
      }
    }
#pragma unroll
    for (int ks = 0; ks < 4; ++ks) {               // P pack + vectorized store
      bf16x4 pk;
#pragma unroll
      for (int r = 0; r < 4; ++r) pk[r] = (bf16)exp2f(st[ks][r] - mq);
      const int col = (((ks * 2 + (lg >> 1)) ^ swz) << 3) + ((lg & 1) << 2);
      *(bf16x4*)&Pl[w][lr][col] = pk;
    }

    // --- PV + denominators ---
    const bf16x8 pf0 = *(const bf16x8*)&Pl[w][lr][(lg ^ swz) << 3];
    const bf16x8 pf1 = *(const bf16x8*)&Pl[w][lr][((lg + 4) ^ swz) << 3];
    __builtin_amdgcn_s_setprio(1);
#pragma unroll
    for (int jn = 0; jn < 4; ++jn) {
      const bf16x8 vf0 = *(const bf16x8*)&Vt[jn * 16 + lr][(lg ^ swz) << 3];
      const bf16x8 vf1 = *(const bf16x8*)&Vt[jn * 16 + lr][((lg + 4) ^ swz) << 3];
      acc[jn] = MFMA16(pf0, vf0, acc[jn]);
      acc[jn] = MFMA16(pf1, vf1, acc[jn]);
    }
    accl = MFMA16(pf0, ones8, accl);
    accl = MFMA16(pf1, ones8, accl);
    __builtin_amdgcn_s_setprio(0);
    __syncthreads();
  }

  const int bb = bh >> 4, hh = bh & 15;
#pragma unroll
  for (int r = 0; r < 4; ++r) {
    const float inv = 1.f / accl[r];
    const size_t rowg = (size_t)bb * 2048 + q0 + w * 16 + lg * 4 + r;
#pragma unroll
    for (int jn = 0; jn < 4; ++jn)
      ctxo[rowg * 1024 + hh * 64 + jn * 16 + lr] = (bf16)(acc[jn][r] * inv);
  }
}

// ---------- fused split-K reduce + bias + residual + LayerNorm --------------
// p: two fp32 partial planes [4096][1024]; resid bf16; out bf16.
__global__ __launch_bounds__(256) void ln2_kernel(const float* __restrict__ p,
                                                  const bf16* __restrict__ resid,
                                                  const float* __restrict__ bias,
                                                  const float* __restrict__ g,
                                                  const float* __restrict__ be,
                                                  bf16* __restrict__ xo) {
  const int row = blockIdx.x, tid = threadIdx.x;
  const float4 a0 = ((const float4*)(p + (size_t)row * 1024))[tid];
  const float4 a1 = ((const float4*)(p + (size_t)4096 * 1024 + (size_t)row * 1024))[tid];
  const bf16x4 rv = *(const bf16x4*)&resid[(size_t)row * 1024 + tid * 4];
  const float4 bb = ((const float4*)bias)[tid];
  float4 v;
  v.x = a0.x + a1.x + bb.x + (float)rv[0];
  v.y = a0.y + a1.y + bb.y + (float)rv[1];
  v.z = a0.z + a1.z + bb.z + (float)rv[2];
  v.w = a0.w + a1.w + bb.w + (float)rv[3];
  float s = v.x + v.y + v.z + v.w;
  float s2 = v.x * v.x + v.y * v.y + v.z * v.z + v.w * v.w;
#pragma unroll
  for (int o = 32; o > 0; o >>= 1) { s += __shfl_down(s, o); s2 += __shfl_down(s2, o); }
  __shared__ float red[8];
  if ((tid & 63) == 0) { red[tid >> 6] = s; red[4 + (tid >> 6)] = s2; }
  __syncthreads();
  s = red[0] + red[1] + red[2] + red[3];
  s2 = red[4] + red[5] + red[6] + red[7];
  const float mean = s * (1.f / 1024.f);
  const float var = s2 * (1.f / 1024.f) - mean * mean;
  const float rstd = rsqrtf(var + 1e-5f);
  const float4 gv = ((const float4*)g)[tid];
  const float4 bv = ((const float4*)be)[tid];
  bf16x4 o4;
  o4[0] = (bf16)((v.x - mean) * rstd * gv.x + bv.x);
  o4[1] = (bf16)((v.y - mean) * rstd * gv.y + bv.y);
  o4[2] = (bf16)((v.z - mean) * rstd * gv.z + bv.z);
  o4[3] = (bf16)((v.w - mean) * rstd * gv.w + bv.w);
  *(bf16x4*)&xo[(size_t)row * 1024 + tid * 4] = o4;
}

// ------------------------------ bf16 -> fp32 --------------------------------
__global__ __launch_bounds__(256) void to_f32_kernel(const bf16* __restrict__ x,
                                                     float* __restrict__ o) {
  const size_t i = ((size_t)blockIdx.x * 256 + threadIdx.x) * 4;
  const bf16x4 v = *(const bf16x4*)&x[i];
  float4 f;
  f.x = (float)v[0]; f.y = (float)v[1]; f.z = (float)v[2]; f.w = (float)v[3];
  *(float4*)&o[i] = f;
}

// ----------------------------------------------------------------------------
extern "C" void kernel_launch(void* const* d_in, const int* in_sizes, int n_in,
                              void* d_out, int out_size, void* d_ws, size_t ws_size,
                              hipStream_t stream) {
  const int* tokens = (const int*)d_in[0];
  const float* emb = (const float*)d_in[2];
  const float* Wq = (const float*)d_in[3];
  const float* bq = (const float*)d_in[4];
  const float* Wk = (const float*)d_in[5];
  const float* bk = (const float*)d_in[6];
  const float* Wv = (const float*)d_in[7];
  const float* bv = (const float*)d_in[8];
  const float* Wo = (const float*)d_in[9];
  const float* bo = (const float*)d_in[10];
  const float* W1 = (const float*)d_in[11];
  const float* b1 = (const float*)d_in[12];
  const float* W2 = (const float*)d_in[13];
  const float* b2 = (const float*)d_in[14];
  const float* g1 = (const float*)d_in[15];
  const float* be1 = (const float*)d_in[16];
  const float* g2 = (const float*)d_in[17];
  const float* be2 = (const float*)d_in[18];

  char* p = (char*)d_ws;
  auto carve = [&](size_t bytes) { char* r = p; p += (bytes + 255) & ~(size_t)255; return r; };
  bf16* wt_qkv = (bf16*)carve((size_t)3072 * 1024 * 2);
  bf16* wt_o   = (bf16*)carve((size_t)1024 * 1024 * 2);
  bf16* wt_1   = (bf16*)carve((size_t)4096 * 1024 * 2);
  bf16* wt_2   = (bf16*)carve((size_t)1024 * 4096 * 2);
  bf16* xb     = (bf16*)carve((size_t)4096 * 1024 * 2);
  bf16* qb     = (bf16*)carve((size_t)4096 * 1024 * 2);
  bf16* kb     = (bf16*)carve((size_t)4096 * 1024 * 2);
  bf16* vb     = (bf16*)carve((size_t)4096 * 1024 * 2);
  bf16* vtb    = (bf16*)carve((size_t)4096 * 1024 * 2);
  bf16* ctxb   = (bf16*)carve((size_t)4096 * 1024 * 2);
  float* pb    = (float*)carve((size_t)2 * 4096 * 1024 * 4);   // split-K partials
  bf16* hb     = (bf16*)carve((size_t)4096 * 4096 * 2);

  embed_kernel<<<4096, 256, 0, stream>>>(tokens, emb, xb);

  for (int l = 0; l < 6; ++l) {
    TArgs ta;
    ta.j[0] = { Wq + (size_t)l * 1024 * 1024, wt_qkv,                  1024, 1024, 0 };
    ta.j[1] = { Wk + (size_t)l * 1024 * 1024, wt_qkv + 1024 * 1024,    1024, 1024, 1024 };
    ta.j[2] = { Wv + (size_t)l * 1024 * 1024, wt_qkv + 2 * 1024 * 1024,1024, 1024, 2048 };
    ta.j[3] = { Wo + (size_t)l * 1024 * 1024, wt_o,                    1024, 1024, 3072 };
    ta.j[4] = { W1 + (size_t)l * 1024 * 4096, wt_1,                    1024, 4096, 4096 };
    ta.j[5] = { W2 + (size_t)l * 4096 * 1024, wt_2,                    4096, 1024, 8192 };
    wtrans_kernel<<<12288, 256, 0, stream>>>(ta);

    gemm_bt<0><<<768, 256, 0, stream>>>(xb, wt_qkv, 1024, 3072, 24,
        bq + (size_t)l * 1024, bk + (size_t)l * 1024, bv + (size_t)l * 1024,
        nullptr, qb, kb, vb);

    vtrans_kernel<<<dim3(32, 32), 256, 0, stream>>>(vb, vtb);

    attn_kernel<<<dim3(32, 32), 256, 0, stream>>>(qb, kb, vtb, ctxb);

    // O-proj: split-K=2 over K=1024
    gemm_sk<<<dim3(256, 2), 256, 0, stream>>>(ctxb, wt_o, 1024, 512, 8, pb);
    ln2_kernel<<<4096, 256, 0, stream>>>(pb, xb, bo + (size_t)l * 1024,
        g1 + (size_t)l * 1024, be1 + (size_t)l * 1024, xb);

    gemm_bt<2><<<1024, 256, 0, stream>>>(xb, wt_1, 1024, 4096, 32,
        b1 + (size_t)l * 4096, nullptr, nullptr, hb,
        nullptr, nullptr, nullptr);

    // FFN2: split-K=2 over K=4096
    gemm_sk<<<dim3(256, 2), 256, 0, stream>>>(hb, wt_2, 4096, 2048, 8, pb);
    ln2_kernel<<<4096, 256, 0, stream>>>(pb, xb, b2 + (size_t)l * 1024,
        g2 + (size_t)l * 1024, be2 + (size_t)l * 1024, xb);
  }

  to_f32_kernel<<<4096, 256, 0, stream>>>(xb, (float*)d_out);
}

// Round 6
// 1582.792 us; speedup vs baseline: 3.7909x; 1.0886x over previous
//
#include <hip/hip_runtime.h>
#include <hip/hip_bf16.h>
#include <cstdint>
#include <cstddef>

// ---------------------------------------------------------------------------
// Transformer encoder, 6 layers: B=2,S=2048,D=1024,H=16,HD=64,F=4096.
// QKV+FFN1: 256^2-tile 8-wave GEMM, counted-vmcnt double buffer (T2+T3+T4+T5).
// O-proj/FFN2: split-K 128^2. Flash attention (swapped QK^T, T2 swizzle).
// ---------------------------------------------------------------------------

typedef __bf16 bf16;
typedef __bf16 bf16x2 __attribute__((ext_vector_type(2)));
typedef __bf16 bf16x4 __attribute__((ext_vector_type(4)));
typedef __bf16 bf16x8 __attribute__((ext_vector_type(8)));
typedef float  f32x4  __attribute__((ext_vector_type(4)));

#define MFMA16(a, b, c) __builtin_amdgcn_mfma_f32_16x16x32_bf16((a), (b), (c), 0, 0, 0)

static __device__ __forceinline__ void load_lds16(const void* g, void* l) {
  __builtin_amdgcn_global_load_lds((const __attribute__((address_space(1))) void*)g,
                                   (__attribute__((address_space(3))) void*)l, 16, 0, 0);
}

#define BAR()   __builtin_amdgcn_s_barrier()
#define SCH0()  __builtin_amdgcn_sched_barrier(0)
#define VMCNT8() asm volatile("s_waitcnt vmcnt(8)" ::: "memory")
#define VMCNT0() asm volatile("s_waitcnt vmcnt(0)" ::: "memory")

// ---------------- embedding + positional encoding -> bf16 x ----------------
__global__ __launch_bounds__(256) void embed_kernel(const int* __restrict__ tok,
                                                    const float* __restrict__ emb,
                                                    bf16* __restrict__ xo) {
  const int row = blockIdx.x;          // b*2048 + s
  const int s = row & 2047;
  const int t = tok[row];
  const int d0 = threadIdx.x * 4;
  const float4 e = *(const float4*)&emb[(size_t)t * 1024 + d0];
  const float* ef = (const float*)&e;
  bf16x4 o4;
#pragma unroll
  for (int j = 0; j < 4; ++j) {
    const int d = d0 + j;
    const float div = __expf(-(float)(d & ~1) * 0.00899447301950864f); // ln(1e4)/1024
    const float arg = (float)s * div;
    const float pe = (d & 1) ? cosf(arg) : sinf(arg);
    o4[j] = (bf16)(ef[j] + pe);
  }
  *(bf16x4*)&xo[(size_t)row * 1024 + d0] = o4;
}

// ------------- weight transpose: fp32 [K][N] -> bf16 [N][K], batched --------
struct TJob { const float* src; bf16* dst; int K; int N; int t0; };
struct TArgs { TJob j[6]; };

__global__ __launch_bounds__(256) void wtrans_kernel(TArgs a) {
  __shared__ float t[32][33];
  const int blk = blockIdx.x;
  const float* src = a.j[0].src; bf16* dst = a.j[0].dst;
  int K = a.j[0].K, N = a.j[0].N, t0 = a.j[0].t0;
#pragma unroll
  for (int q = 1; q < 6; ++q)
    if (blk >= a.j[q].t0) { src = a.j[q].src; dst = a.j[q].dst; K = a.j[q].K; N = a.j[q].N; t0 = a.j[q].t0; }
  const int tj = blk - t0;
  const int tilesK = K >> 5;
  const int tk = (tj % tilesK) << 5;
  const int tn = (tj / tilesK) << 5;
  const int lx = threadIdx.x & 31, ly = threadIdx.x >> 5;
#pragma unroll
  for (int i = 0; i < 4; ++i)
    t[ly + 8 * i][lx] = src[(size_t)(tk + ly + 8 * i) * N + tn + lx];
  __syncthreads();
#pragma unroll
  for (int i = 0; i < 4; ++i)
    dst[(size_t)(tn + ly + 8 * i) * K + tk + lx] = (bf16)t[lx][ly + 8 * i];
}

// -------- V transpose per layer: [bh][s][64] bf16 -> [bh][64][s] bf16 -------
__global__ __launch_bounds__(256) void vtrans_kernel(const bf16* __restrict__ v,
                                                     bf16* __restrict__ vt) {
  __shared__ bf16 t[64][72];
  const int bh = blockIdx.y;
  const int s0 = blockIdx.x * 64;
  const int tid = threadIdx.x;
#pragma unroll
  for (int it = 0; it < 2; ++it) {
    const int idx = tid + it * 256;
    const int sr = idx >> 3, h8 = (idx & 7) * 8;
    *(bf16x8*)&t[sr][h8] = *(const bf16x8*)&v[((size_t)bh * 2048 + s0 + sr) * 64 + h8];
  }
  __syncthreads();
#pragma unroll
  for (int it = 0; it < 2; ++it) {
    const int idx = tid + it * 256;
    const int hd = idx >> 3, s8 = (idx & 7) * 8;
    bf16x8 o;
#pragma unroll
    for (int j = 0; j < 8; ++j) o[j] = t[s8 + j][hd];
    *(bf16x8*)&vt[((size_t)bh * 64 + hd) * 2048 + s0 + s8] = o;
  }
}

// ================= 256x256-tile 8-wave GEMM, counted-vmcnt =================
// 512 threads, waves (wm = w>>2 in [0,2), wn = w&3 in [0,4)); per-wave 128x64.
// LDS: 2 bufs x (A 32KB + B 32KB) = 128KB, BK=64.
// Swizzle (both sides, involution): off ^= ((off>>7)&7)<<4  (row&7 -> 16B slot).
// EPI 0: +bias, scatter q/k/v.  EPI 2: +bias, ReLU -> bf16 (Nn stride).
static __device__ __forceinline__ bf16x8 ldsfrag(const bf16* base, int row, int colb) {
  int off = row * 128 + colb;
  off ^= ((off >> 7) & 7) << 4;
  return *(const bf16x8*)((const char*)base + off);
}

static __device__ __forceinline__ void stage_tile(const bf16* __restrict__ Ag,
    const bf16* __restrict__ Bg, int Kstr, int kt, bf16* lA, bf16* lB, int tid) {
  const char* wbaseA = (const char*)lA + ((tid >> 6) << 10);
  const char* wbaseB = (const char*)lB + ((tid >> 6) << 10);
#pragma unroll
  for (int s = 0; s < 4; ++s) {
    const int L = s * 8192 + tid * 16;
    const int off = L ^ (((L >> 7) & 7) << 4);
    load_lds16(Ag + (size_t)(off >> 7) * Kstr + kt * 64 + ((off & 127) >> 1),
               (void*)(wbaseA + s * 8192));
  }
#pragma unroll
  for (int s = 0; s < 4; ++s) {
    const int L = s * 8192 + tid * 16;
    const int off = L ^ (((L >> 7) & 7) << 4);
    load_lds16(Bg + (size_t)(off >> 7) * Kstr + kt * 64 + ((off & 127) >> 1),
               (void*)(wbaseB + s * 8192));
  }
}

static __device__ __forceinline__ void compute_tile(const bf16* lA, const bf16* lB,
    int wm, int wn, int lr, int lg, f32x4 (&acc)[8][4]) {
  bf16x8 bfr[4][2];
#pragma unroll
  for (int n = 0; n < 4; ++n)
#pragma unroll
    for (int kk = 0; kk < 2; ++kk)
      bfr[n][kk] = ldsfrag(lB, wn * 64 + n * 16 + lr, kk * 64 + lg * 16);
#pragma unroll
  for (int m = 0; m < 8; ++m) {
    const bf16x8 a0 = ldsfrag(lA, wm * 128 + m * 16 + lr, lg * 16);
    const bf16x8 a1 = ldsfrag(lA, wm * 128 + m * 16 + lr, 64 + lg * 16);
    __builtin_amdgcn_s_setprio(1);
#pragma unroll
    for (int n = 0; n < 4; ++n) {
      acc[m][n] = MFMA16(a0, bfr[n][0], acc[m][n]);
      acc[m][n] = MFMA16(a1, bfr[n][1], acc[m][n]);
    }
    __builtin_amdgcn_s_setprio(0);
  }
}

template <int EPI>
__global__ __launch_bounds__(512, 2) void gemm256(
    const bf16* __restrict__ A, const bf16* __restrict__ Bt, int Kk, int Nn, int nbx,
    const float* __restrict__ bias0, const float* __restrict__ bias1,
    const float* __restrict__ bias2, bf16* __restrict__ outb,
    bf16* __restrict__ q_out, bf16* __restrict__ k_out, bf16* __restrict__ v_out) {
  __shared__ __align__(16) bf16 lds[4][16384];   // A0,B0,A1,B1 (32KB each)
  const int cpx = gridDim.x >> 3;
  const int wg = (blockIdx.x & 7) * cpx + (blockIdx.x >> 3);
  const int bx = wg % nbx, by = wg / nbx;
  const int tid = threadIdx.x;
  const int lane = tid & 63, wave = tid >> 6;
  const int lr = lane & 15, lg = lane >> 4;
  const int wm = wave >> 2, wn = wave & 3;
  const int m0 = by * 256, n0 = bx * 256;

  const bf16* Ag = A + (size_t)m0 * Kk;
  const bf16* Bg = Bt + (size_t)n0 * Kk;
  bf16* LA0 = lds[0]; bf16* LB0 = lds[1];
  bf16* LA1 = lds[2]; bf16* LB1 = lds[3];

  f32x4 acc[8][4] = {};
  const int T = Kk >> 6;

  stage_tile(Ag, Bg, Kk, 0, LA0, LB0, tid);
  stage_tile(Ag, Bg, Kk, 1, LA1, LB1, tid);
  VMCNT8(); BAR(); SCH0();

  for (int t = 0; t + 3 < T; t += 2) {
    compute_tile(LA0, LB0, wm, wn, lr, lg, acc);
    BAR(); SCH0();                       // all waves done reading buf0
    stage_tile(Ag, Bg, Kk, t + 2, LA0, LB0, tid);
    VMCNT8(); BAR(); SCH0();             // tile t+1 landed everywhere
    compute_tile(LA1, LB1, wm, wn, lr, lg, acc);
    BAR(); SCH0();
    stage_tile(Ag, Bg, Kk, t + 3, LA1, LB1, tid);
    VMCNT8(); BAR(); SCH0();
  }
  compute_tile(LA0, LB0, wm, wn, lr, lg, acc);   // tile T-2
  VMCNT0(); BAR(); SCH0();                       // tile T-1 landed
  compute_tile(LA1, LB1, wm, wn, lr, lg, acc);   // tile T-1

#pragma unroll
  for (int m = 0; m < 8; ++m)
#pragma unroll
    for (int n = 0; n < 4; ++n)
#pragma unroll
      for (int r = 0; r < 4; ++r) {
        const int row = m0 + wm * 128 + m * 16 + lg * 4 + r;
        const int col = n0 + wn * 64 + n * 16 + lr;
        float val = acc[m][n][r];
        if (EPI == 0) {
          const int which = col >> 10, hc = col & 1023;
          const float* bs = (which == 0) ? bias0 : (which == 1) ? bias1 : bias2;
          bf16* dst = (which == 0) ? q_out : (which == 1) ? k_out : v_out;
          val += bs[hc];
          const int b = row >> 11, s = row & 2047;
          const int h = hc >> 6, hd = hc & 63;
          dst[(((size_t)b * 16 + h) * 2048 + s) * 64 + hd] = (bf16)val;
        } else {
          val += bias0[col];
          outb[(size_t)row * Nn + col] = (bf16)(val > 0.f ? val : 0.f);
        }
      }
}

// -------- split-K GEMM, 128x128 tile, N=1024: partial fp32, no bias --------
__global__ __launch_bounds__(256) void gemm_sk(
    const bf16* __restrict__ A, const bf16* __restrict__ Bt,
    int Kstride, int Kloop, int nbx, float* __restrict__ pout) {
  __shared__ __align__(16) bf16 As[128 * 32];
  __shared__ __align__(16) bf16 Bs[128 * 32];
  const int bz = blockIdx.y;
  const bf16* Ab = A + (size_t)bz * Kloop;
  const bf16* Bb = Bt + (size_t)bz * Kloop;
  float* pb = pout + (size_t)bz * 4096 * 1024;
  const int cpx = gridDim.x >> 3;
  const int wg = (blockIdx.x & 7) * cpx + (blockIdx.x >> 3);
  const int bx = wg % nbx, by = wg / nbx;
  const int tid = threadIdx.x;
  const int lane = tid & 63;
  const int wave = tid >> 6;
  const int lr = lane & 15, lg = lane >> 4;
  const int m0 = by * 128;
  const int n0 = bx * 128;
  const int wr = (wave >> 1) * 64, wc = (wave & 1) * 64;

  f32x4 acc[4][4] = {};

  const int idx0 = tid, idx1 = tid + 256;
  const char* gA0 = (const char*)(Ab + (size_t)(m0 + (idx0 >> 2)) * Kstride) + (idx0 & 3) * 16;
  const char* gA1 = (const char*)(Ab + (size_t)(m0 + (idx1 >> 2)) * Kstride) + (idx1 & 3) * 16;
  const char* gB0 = (const char*)(Bb + (size_t)(n0 + (idx0 >> 2)) * Kstride) + (idx0 & 3) * 16;
  const char* gB1 = (const char*)(Bb + (size_t)(n0 + (idx1 >> 2)) * Kstride) + (idx1 & 3) * 16;
  bf16* lA0 = &As[(wave * 64) * 8];
  bf16* lA1 = &As[(256 + wave * 64) * 8];
  bf16* lB0 = &Bs[(wave * 64) * 8];
  bf16* lB1 = &Bs[(256 + wave * 64) * 8];

  const int ksteps = Kloop >> 5;
  for (int kt = 0; kt < ksteps; ++kt) {
    load_lds16(gA0, lA0); load_lds16(gA1, lA1);
    load_lds16(gB0, lB0); load_lds16(gB1, lB1);
    gA0 += 64; gA1 += 64; gB0 += 64; gB1 += 64;
    __syncthreads();
    bf16x8 af[2], bfr[2];
    bf16x8 af2[2], bfr2[2];
#pragma unroll
    for (int i = 0; i < 4; ++i) {
      bf16x8 a = *(const bf16x8*)&As[(wr + i * 16 + lr) * 32 + lg * 8];
      if (i < 2) af[i] = a; else af2[i - 2] = a;
    }
#pragma unroll
    for (int j = 0; j < 4; ++j) {
      bf16x8 b = *(const bf16x8*)&Bs[(wc + j * 16 + lr) * 32 + lg * 8];
      if (j < 2) bfr[j] = b; else bfr2[j - 2] = b;
    }
#pragma unroll
    for (int i = 0; i < 4; ++i)
#pragma unroll
      for (int j = 0; j < 4; ++j) {
        const bf16x8 a = (i < 2) ? af[i & 1] : af2[i & 1];
        const bf16x8 b = (j < 2) ? bfr[j & 1] : bfr2[j & 1];
        acc[i][j] = MFMA16(a, b, acc[i][j]);
      }
    __syncthreads();
  }

#pragma unroll
  for (int i = 0; i < 4; ++i)
#pragma unroll
    for (int j = 0; j < 4; ++j)
#pragma unroll
      for (int r = 0; r < 4; ++r) {
        const int row = m0 + wr + i * 16 + lg * 4 + r;
        const int col = n0 + wc + j * 16 + lr;
        pb[(size_t)row * 1024 + col] = acc[i][j][r];
      }
}

// ------------------------- flash attention (per b,h) ------------------------
__global__ __launch_bounds__(256) void attn_kernel(const bf16* __restrict__ q,
                                                   const bf16* __restrict__ k,
                                                   const bf16* __restrict__ vt,
                                                   bf16* __restrict__ ctxo) {
  __shared__ __align__(16) bf16 Kl[64][64];
  __shared__ __align__(16) bf16 Vt[64][64];   // rows = hd, cols = key
  __shared__ __align__(16) bf16 Pl[4][16][64];
  const int tid = threadIdx.x;
  const int lane = tid & 63, w = tid >> 6;
  const int lr = lane & 15, lg = lane >> 4;
  const int swz = lr & 7;
  const int bh = blockIdx.y;
  const int q0 = blockIdx.x * 64;

  const bf16* qp = q + ((size_t)bh * 2048 + q0 + w * 16) * 64;
  bf16x8 qf0 = *(const bf16x8*)&qp[lr * 64 + lg * 8];
  bf16x8 qf1 = *(const bf16x8*)&qp[lr * 64 + lg * 8 + 32];
  const float qs = 0.18033688011112042f;      // (1/8)*log2(e)
#pragma unroll
  for (int j = 0; j < 8; ++j) {
    qf0[j] = (bf16)((float)qf0[j] * qs);
    qf1[j] = (bf16)((float)qf1[j] * qs);
  }
  bf16x8 ones8;
#pragma unroll
  for (int j = 0; j < 8; ++j) ones8[j] = (bf16)1.0f;

  const bf16* kbase = k + (size_t)bh * 2048 * 64;
  const bf16* vtb = vt + (size_t)bh * 64 * 2048;

  const int sr0 = tid >> 3, sr1 = sr0 + 32;
  const int c0 = (tid & 7) * 8;
  const int cs0 = c0 ^ ((sr0 & 7) << 3);
  const int cs1 = c0 ^ ((sr1 & 7) << 3);

  f32x4 acc[4] = {};
  f32x4 accl = {};
  float mq = -1e30f;

  bf16x8 kr[2][2], vr[2][2];
  kr[0][0] = *(const bf16x8*)&kbase[(size_t)sr0 * 64 + c0];
  kr[0][1] = *(const bf16x8*)&kbase[(size_t)sr1 * 64 + c0];
  vr[0][0] = *(const bf16x8*)&vtb[(size_t)sr0 * 2048 + c0];
  vr[0][1] = *(const bf16x8*)&vtb[(size_t)sr1 * 2048 + c0];

#pragma unroll 2
  for (int c = 0; c < 32; ++c) {
    const int pp = c & 1;
    *(bf16x8*)&Kl[sr0][cs0] = kr[pp][0];
    *(bf16x8*)&Kl[sr1][cs1] = kr[pp][1];
    *(bf16x8*)&Vt[sr0][cs0] = vr[pp][0];
    *(bf16x8*)&Vt[sr1][cs1] = vr[pp][1];
    if (c + 1 < 32) {
      const int key0n = (c + 1) * 64;
      kr[pp ^ 1][0] = *(const bf16x8*)&kbase[(size_t)(key0n + sr0) * 64 + c0];
      kr[pp ^ 1][1] = *(const bf16x8*)&kbase[(size_t)(key0n + sr1) * 64 + c0];
      vr[pp ^ 1][0] = *(const bf16x8*)&vtb[(size_t)sr0 * 2048 + key0n + c0];
      vr[pp ^ 1][1] = *(const bf16x8*)&vtb[(size_t)sr1 * 2048 + key0n + c0];
    }
    __syncthreads();

    f32x4 st[4];
    __builtin_amdgcn_s_setprio(1);
#pragma unroll
    for (int ks = 0; ks < 4; ++ks) {
      const bf16x8 kf0 = *(const bf16x8*)&Kl[ks * 16 + lr][(lg ^ swz) << 3];
      const bf16x8 kf1 = *(const bf16x8*)&Kl[ks * 16 + lr][((lg + 4) ^ swz) << 3];
      f32x4 sa = {};
      sa = MFMA16(kf0, qf0, sa);
      sa = MFMA16(kf1, qf1, sa);
      st[ks] = sa;
    }
    __builtin_amdgcn_s_setprio(0);

    float mx = st[0][0];
#pragma unroll
    for (int ks = 0; ks < 4; ++ks)
#pragma unroll
      for (int r = 0; r < 4; ++r) mx = fmaxf(mx, st[ks][r]);
    mx = fmaxf(mx, __shfl_xor(mx, 16));
    mx = fmaxf(mx, __shfl_xor(mx, 32));
    if (!__all(mx - mq <= 8.0f)) {
      const float resc = exp2f(mq - mx);
      mq = mx;
      float rq[4];
#pragma unroll
      for (int r = 0; r < 4; ++r) rq[r] = __shfl(resc, lg * 4 + r);
#pragma unroll
      for (int r = 0; r < 4; ++r) {
        accl[r] *= rq[r];
#pragma unroll
        for (int jn = 0; jn < 4; ++jn) acc[jn][r] *= rq[r];
      }
    }
#pragma unroll
    for (int ks = 0; ks < 4; ++ks) {
      bf16x4 pk;
#pragma unroll
      for (int r = 0; r < 4; ++r) pk[r] = (bf16)exp2f(st[ks][r] - mq);
      const int col = (((ks * 2 + (lg >> 1)) ^ swz) << 3) + ((lg & 1) << 2);
      *(bf16x4*)&Pl[w][lr][col] = pk;
    }

    const bf16x8 pf0 = *(const bf16x8*)&Pl[w][lr][(lg ^ swz) << 3];
    const bf16x8 pf1 = *(const bf16x8*)&Pl[w][lr][((lg + 4) ^ swz) << 3];
    __builtin_amdgcn_s_setprio(1);
#pragma unroll
    for (int jn = 0; jn < 4; ++jn) {
      const bf16x8 vf0 = *(const bf16x8*)&Vt[jn * 16 + lr][(lg ^ swz) << 3];
      const bf16x8 vf1 = *(const bf16x8*)&Vt[jn * 16 + lr][((lg + 4) ^ swz) << 3];
      acc[jn] = MFMA16(pf0, vf0, acc[jn]);
      acc[jn] = MFMA16(pf1, vf1, acc[jn]);
    }
    accl = MFMA16(pf0, ones8, accl);
    accl = MFMA16(pf1, ones8, accl);
    __builtin_amdgcn_s_setprio(0);
    __syncthreads();
  }

  const int bb = bh >> 4, hh = bh & 15;
#pragma unroll
  for (int r = 0; r < 4; ++r) {
    const float inv = 1.f / accl[r];
    const size_t rowg = (size_t)bb * 2048 + q0 + w * 16 + lg * 4 + r;
#pragma unroll
    for (int jn = 0; jn < 4; ++jn)
      ctxo[rowg * 1024 + hh * 64 + jn * 16 + lr] = (bf16)(acc[jn][r] * inv);
  }
}

// ---------- fused split-K reduce + bias + residual + LayerNorm --------------
__global__ __launch_bounds__(256) void ln2_kernel(const float* __restrict__ p,
                                                  const bf16* __restrict__ resid,
                                                  const float* __restrict__ bias,
                                                  const float* __restrict__ g,
                                                  const float* __restrict__ be,
                                                  bf16* __restrict__ xo) {
  const int row = blockIdx.x, tid = threadIdx.x;
  const float4 a0 = ((const float4*)(p + (size_t)row * 1024))[tid];
  const float4 a1 = ((const float4*)(p + (size_t)4096 * 1024 + (size_t)row * 1024))[tid];
  const bf16x4 rv = *(const bf16x4*)&resid[(size_t)row * 1024 + tid * 4];
  const float4 bb = ((const float4*)bias)[tid];
  float4 v;
  v.x = a0.x + a1.x + bb.x + (float)rv[0];
  v.y = a0.y + a1.y + bb.y + (float)rv[1];
  v.z = a0.z + a1.z + bb.z + (float)rv[2];
  v.w = a0.w + a1.w + bb.w + (float)rv[3];
  float s = v.x + v.y + v.z + v.w;
  float s2 = v.x * v.x + v.y * v.y + v.z * v.z + v.w * v.w;
#pragma unroll
  for (int o = 32; o > 0; o >>= 1) { s += __shfl_down(s, o); s2 += __shfl_down(s2, o); }
  __shared__ float red[8];
  if ((tid & 63) == 0) { red[tid >> 6] = s; red[4 + (tid >> 6)] = s2; }
  __syncthreads();
  s = red[0] + red[1] + red[2] + red[3];
  s2 = red[4] + red[5] + red[6] + red[7];
  const float mean = s * (1.f / 1024.f);
  const float var = s2 * (1.f / 1024.f) - mean * mean;
  const float rstd = rsqrtf(var + 1e-5f);
  const float4 gv = ((const float4*)g)[tid];
  const float4 bv = ((const float4*)be)[tid];
  bf16x4 o4;
  o4[0] = (bf16)((v.x - mean) * rstd * gv.x + bv.x);
  o4[1] = (bf16)((v.y - mean) * rstd * gv.y + bv.y);
  o4[2] = (bf16)((v.z - mean) * rstd * gv.z + bv.z);
  o4[3] = (bf16)((v.w - mean) * rstd * gv.w + bv.w);
  *(bf16x4*)&xo[(size_t)row * 1024 + tid * 4] = o4;
}

// ------------------------------ bf16 -> fp32 --------------------------------
__global__ __launch_bounds__(256) void to_f32_kernel(const bf16* __restrict__ x,
                                                     float* __restrict__ o) {
  const size_t i = ((size_t)blockIdx.x * 256 + threadIdx.x) * 4;
  const bf16x4 v = *(const bf16x4*)&x[i];
  float4 f;
  f.x = (float)v[0]; f.y = (float)v[1]; f.z = (float)v[2]; f.w = (float)v[3];
  *(float4*)&o[i] = f;
}

// ----------------------------------------------------------------------------
extern "C" void kernel_launch(void* const* d_in, const int* in_sizes, int n_in,
                              void* d_out, int out_size, void* d_ws, size_t ws_size,
                              hipStream_t stream) {
  const int* tokens = (const int*)d_in[0];
  const float* emb = (const float*)d_in[2];
  const float* Wq = (const float*)d_in[3];
  const float* bq = (const float*)d_in[4];
  const float* Wk = (const float*)d_in[5];
  const float* bk = (const float*)d_in[6];
  const float* Wv = (const float*)d_in[7];
  const float* bv = (const float*)d_in[8];
  const float* Wo = (const float*)d_in[9];
  const float* bo = (const float*)d_in[10];
  const float* W1 = (const float*)d_in[11];
  const float* b1 = (const float*)d_in[12];
  const float* W2 = (const float*)d_in[13];
  const float* b2 = (const float*)d_in[14];
  const float* g1 = (const float*)d_in[15];
  const float* be1 = (const float*)d_in[16];
  const float* g2 = (const float*)d_in[17];
  const float* be2 = (const float*)d_in[18];

  char* p = (char*)d_ws;
  auto carve = [&](size_t bytes) { char* r = p; p += (bytes + 255) & ~(size_t)255; return r; };
  bf16* wt_qkv = (bf16*)carve((size_t)3072 * 1024 * 2);
  bf16* wt_o   = (bf16*)carve((size_t)1024 * 1024 * 2);
  bf16* wt_1   = (bf16*)carve((size_t)4096 * 1024 * 2);
  bf16* wt_2   = (bf16*)carve((size_t)1024 * 4096 * 2);
  bf16* xb     = (bf16*)carve((size_t)4096 * 1024 * 2);
  bf16* qb     = (bf16*)carve((size_t)4096 * 1024 * 2);
  bf16* kb     = (bf16*)carve((size_t)4096 * 1024 * 2);
  bf16* vb     = (bf16*)carve((size_t)4096 * 1024 * 2);
  bf16* vtb    = (bf16*)carve((size_t)4096 * 1024 * 2);
  bf16* ctxb   = (bf16*)carve((size_t)4096 * 1024 * 2);
  float* pb    = (float*)carve((size_t)2 * 4096 * 1024 * 4);   // split-K partials
  bf16* hb     = (bf16*)carve((size_t)4096 * 4096 * 2);

  embed_kernel<<<4096, 256, 0, stream>>>(tokens, emb, xb);

  for (int l = 0; l < 6; ++l) {
    TArgs ta;
    ta.j[0] = { Wq + (size_t)l * 1024 * 1024, wt_qkv,                  1024, 1024, 0 };
    ta.j[1] = { Wk + (size_t)l * 1024 * 1024, wt_qkv + 1024 * 1024,    1024, 1024, 1024 };
    ta.j[2] = { Wv + (size_t)l * 1024 * 1024, wt_qkv + 2 * 1024 * 1024,1024, 1024, 2048 };
    ta.j[3] = { Wo + (size_t)l * 1024 * 1024, wt_o,                    1024, 1024, 3072 };
    ta.j[4] = { W1 + (size_t)l * 1024 * 4096, wt_1,                    1024, 4096, 4096 };
    ta.j[5] = { W2 + (size_t)l * 4096 * 1024, wt_2,                    4096, 1024, 8192 };
    wtrans_kernel<<<12288, 256, 0, stream>>>(ta);

    // QKV: 256^2 tile, grid 16x12 = 192
    gemm256<0><<<192, 512, 0, stream>>>(xb, wt_qkv, 1024, 3072, 12,
        bq + (size_t)l * 1024, bk + (size_t)l * 1024, bv + (size_t)l * 1024,
        nullptr, qb, kb, vb);

    vtrans_kernel<<<dim3(32, 32), 256, 0, stream>>>(vb, vtb);

    attn_kernel<<<dim3(32, 32), 256, 0, stream>>>(qb, kb, vtb, ctxb);

    // O-proj: split-K=2 over K=1024 (128^2)
    gemm_sk<<<dim3(256, 2), 256, 0, stream>>>(ctxb, wt_o, 1024, 512, 8, pb);
    ln2_kernel<<<4096, 256, 0, stream>>>(pb, xb, bo + (size_t)l * 1024,
        g1 + (size_t)l * 1024, be1 + (size_t)l * 1024, xb);

    // FFN1: 256^2 tile, grid 16x16 = 256
    gemm256<2><<<256, 512, 0, stream>>>(xb, wt_1, 1024, 4096, 16,
        b1 + (size_t)l * 4096, nullptr, nullptr, hb,
        nullptr, nullptr, nullptr);

    // FFN2: split-K=2 over K=4096 (128^2)
    gemm_sk<<<dim3(256, 2), 256, 0, stream>>>(hb, wt_2, 4096, 2048, 8, pb);
    ln2_kernel<<<4096, 256, 0, stream>>>(pb, xb, b2 + (size_t)l * 1024,
        g2 + (size_t)l * 1024, be2 + (size_t)l * 1024, xb);
  }

  to_f32_kernel<<<4096, 256, 0, stream>>>(xb, (float*)d_out);
}

// Round 7
// 1517.012 us; speedup vs baseline: 3.9553x; 1.0434x over previous
//
#include <hip/hip_runtime.h>
#include <hip/hip_bf16.h>
#include <cstdint>
#include <cstddef>

// ---------------------------------------------------------------------------
// Transformer encoder, 6 layers: B=2,S=2048,D=1024,H=16,HD=64,F=4096.
// QKV+FFN1: 256^2-tile 8-wave GEMM, counted-vmcnt double buffer (T2+T3+T4+T5).
// FFN2: same structure, split-K=4 -> fp32 partials. O-proj: split-K 128^2.
// Flash attention (swapped QK^T, T2 swizzle). fp32 LN fused with SK-reduce.
// ---------------------------------------------------------------------------

typedef __bf16 bf16;
typedef __bf16 bf16x2 __attribute__((ext_vector_type(2)));
typedef __bf16 bf16x4 __attribute__((ext_vector_type(4)));
typedef __bf16 bf16x8 __attribute__((ext_vector_type(8)));
typedef float  f32x4  __attribute__((ext_vector_type(4)));

#define MFMA16(a, b, c) __builtin_amdgcn_mfma_f32_16x16x32_bf16((a), (b), (c), 0, 0, 0)

static __device__ __forceinline__ void load_lds16(const void* g, void* l) {
  __builtin_amdgcn_global_load_lds((const __attribute__((address_space(1))) void*)g,
                                   (__attribute__((address_space(3))) void*)l, 16, 0, 0);
}

#define BAR()   __builtin_amdgcn_s_barrier()
#define SCH0()  __builtin_amdgcn_sched_barrier(0)
#define VMCNT8() asm volatile("s_waitcnt vmcnt(8)" ::: "memory")
#define VMCNT0() asm volatile("s_waitcnt vmcnt(0)" ::: "memory")

// ---------------- embedding + positional encoding -> bf16 x ----------------
__global__ __launch_bounds__(256) void embed_kernel(const int* __restrict__ tok,
                                                    const float* __restrict__ emb,
                                                    bf16* __restrict__ xo) {
  const int row = blockIdx.x;          // b*2048 + s
  const int s = row & 2047;
  const int t = tok[row];
  const int d0 = threadIdx.x * 4;
  const float4 e = *(const float4*)&emb[(size_t)t * 1024 + d0];
  const float* ef = (const float*)&e;
  bf16x4 o4;
#pragma unroll
  for (int j = 0; j < 4; ++j) {
    const int d = d0 + j;
    const float div = __expf(-(float)(d & ~1) * 0.00899447301950864f); // ln(1e4)/1024
    const float arg = (float)s * div;
    const float pe = (d & 1) ? cosf(arg) : sinf(arg);
    o4[j] = (bf16)(ef[j] + pe);
  }
  *(bf16x4*)&xo[(size_t)row * 1024 + d0] = o4;
}

// ------------- weight transpose: fp32 [K][N] -> bf16 [N][K], batched --------
struct TJob { const float* src; bf16* dst; int K; int N; int t0; };
struct TArgs { TJob j[6]; };

__global__ __launch_bounds__(256) void wtrans_kernel(TArgs a) {
  __shared__ float t[32][33];
  const int blk = blockIdx.x;
  const float* src = a.j[0].src; bf16* dst = a.j[0].dst;
  int K = a.j[0].K, N = a.j[0].N, t0 = a.j[0].t0;
#pragma unroll
  for (int q = 1; q < 6; ++q)
    if (blk >= a.j[q].t0) { src = a.j[q].src; dst = a.j[q].dst; K = a.j[q].K; N = a.j[q].N; t0 = a.j[q].t0; }
  const int tj = blk - t0;
  const int tilesK = K >> 5;
  const int tk = (tj % tilesK) << 5;
  const int tn = (tj / tilesK) << 5;
  const int lx = threadIdx.x & 31, ly = threadIdx.x >> 5;
#pragma unroll
  for (int i = 0; i < 4; ++i)
    t[ly + 8 * i][lx] = src[(size_t)(tk + ly + 8 * i) * N + tn + lx];
  __syncthreads();
#pragma unroll
  for (int i = 0; i < 4; ++i)
    dst[(size_t)(tn + ly + 8 * i) * K + tk + lx] = (bf16)t[lx][ly + 8 * i];
}

// -------- V transpose per layer: [bh][s][64] bf16 -> [bh][64][s] bf16 -------
__global__ __launch_bounds__(256) void vtrans_kernel(const bf16* __restrict__ v,
                                                     bf16* __restrict__ vt) {
  __shared__ bf16 t[64][72];
  const int bh = blockIdx.y;
  const int s0 = blockIdx.x * 64;
  const int tid = threadIdx.x;
#pragma unroll
  for (int it = 0; it < 2; ++it) {
    const int idx = tid + it * 256;
    const int sr = idx >> 3, h8 = (idx & 7) * 8;
    *(bf16x8*)&t[sr][h8] = *(const bf16x8*)&v[((size_t)bh * 2048 + s0 + sr) * 64 + h8];
  }
  __syncthreads();
#pragma unroll
  for (int it = 0; it < 2; ++it) {
    const int idx = tid + it * 256;
    const int hd = idx >> 3, s8 = (idx & 7) * 8;
    bf16x8 o;
#pragma unroll
    for (int j = 0; j < 8; ++j) o[j] = t[s8 + j][hd];
    *(bf16x8*)&vt[((size_t)bh * 64 + hd) * 2048 + s0 + s8] = o;
  }
}

// ================= 256x256-tile 8-wave GEMM, counted-vmcnt =================
// 512 threads, waves (wm = w>>2, wn = w&3); per-wave 128x64 output.
// LDS: 2 bufs x (A 32KB + B 32KB) = 128KB, BK=64 -> 1 block/CU.
// Swizzle (both sides, involution): off ^= ((off>>7)&7)<<4.
// EPI 0: +bias, scatter q/k/v. EPI 1: fp32 partial (split-K). EPI 2: +bias,ReLU.
static __device__ __forceinline__ bf16x8 ldsfrag(const bf16* base, int row, int colb) {
  int off = row * 128 + colb;
  off ^= ((off >> 7) & 7) << 4;
  return *(const bf16x8*)((const char*)base + off);
}

static __device__ __forceinline__ void stage_tile(const bf16* __restrict__ Ag,
    const bf16* __restrict__ Bg, int Kstr, int kt, bf16* lA, bf16* lB, int tid) {
  const char* wbaseA = (const char*)lA + ((tid >> 6) << 10);
  const char* wbaseB = (const char*)lB + ((tid >> 6) << 10);
#pragma unroll
  for (int s = 0; s < 4; ++s) {
    const int L = s * 8192 + tid * 16;
    const int off = L ^ (((L >> 7) & 7) << 4);
    load_lds16(Ag + (size_t)(off >> 7) * Kstr + kt * 64 + ((off & 127) >> 1),
               (void*)(wbaseA + s * 8192));
  }
#pragma unroll
  for (int s = 0; s < 4; ++s) {
    const int L = s * 8192 + tid * 16;
    const int off = L ^ (((L >> 7) & 7) << 4);
    load_lds16(Bg + (size_t)(off >> 7) * Kstr + kt * 64 + ((off & 127) >> 1),
               (void*)(wbaseB + s * 8192));
  }
}

static __device__ __forceinline__ void compute_tile(const bf16* lA, const bf16* lB,
    int wm, int wn, int lr, int lg, f32x4 (&acc)[8][4]) {
  bf16x8 bfr[4][2];
#pragma unroll
  for (int n = 0; n < 4; ++n)
#pragma unroll
    for (int kk = 0; kk < 2; ++kk)
      bfr[n][kk] = ldsfrag(lB, wn * 64 + n * 16 + lr, kk * 64 + lg * 16);
#pragma unroll
  for (int m = 0; m < 8; ++m) {
    const bf16x8 a0 = ldsfrag(lA, wm * 128 + m * 16 + lr, lg * 16);
    const bf16x8 a1 = ldsfrag(lA, wm * 128 + m * 16 + lr, 64 + lg * 16);
    __builtin_amdgcn_s_setprio(1);
#pragma unroll
    for (int n = 0; n < 4; ++n) {
      acc[m][n] = MFMA16(a0, bfr[n][0], acc[m][n]);
      acc[m][n] = MFMA16(a1, bfr[n][1], acc[m][n]);
    }
    __builtin_amdgcn_s_setprio(0);
  }
}

template <int EPI>
__global__ __launch_bounds__(512, 2) void gemm256(
    const bf16* __restrict__ A, const bf16* __restrict__ Bt,
    int Kstr, int Kloop, int Nn, int nbx,
    const float* __restrict__ bias0, const float* __restrict__ bias1,
    const float* __restrict__ bias2, bf16* __restrict__ outb,
    float* __restrict__ pout,
    bf16* __restrict__ q_out, bf16* __restrict__ k_out, bf16* __restrict__ v_out) {
  __shared__ __align__(16) bf16 lds[4][16384];   // A0,B0,A1,B1 (32KB each)
  const int bz = blockIdx.y;
  const bf16* Abase = A + (size_t)bz * Kloop;
  const bf16* Bbase = Bt + (size_t)bz * Kloop;
  const int cpx = gridDim.x >> 3;
  const int wg = (blockIdx.x & 7) * cpx + (blockIdx.x >> 3);
  const int bx = wg % nbx, by = wg / nbx;
  const int tid = threadIdx.x;
  const int lane = tid & 63, wave = tid >> 6;
  const int lr = lane & 15, lg = lane >> 4;
  const int wm = wave >> 2, wn = wave & 3;
  const int m0 = by * 256, n0 = bx * 256;

  const bf16* Ag = Abase + (size_t)m0 * Kstr;
  const bf16* Bg = Bbase + (size_t)n0 * Kstr;
  bf16* LA0 = lds[0]; bf16* LB0 = lds[1];
  bf16* LA1 = lds[2]; bf16* LB1 = lds[3];

  f32x4 acc[8][4] = {};
  const int T = Kloop >> 6;

  stage_tile(Ag, Bg, Kstr, 0, LA0, LB0, tid);
  stage_tile(Ag, Bg, Kstr, 1, LA1, LB1, tid);
  VMCNT8(); BAR(); SCH0();

  for (int t = 0; t + 3 < T; t += 2) {
    compute_tile(LA0, LB0, wm, wn, lr, lg, acc);
    BAR(); SCH0();                       // all waves done reading buf0
    stage_tile(Ag, Bg, Kstr, t + 2, LA0, LB0, tid);
    VMCNT8(); BAR(); SCH0();             // tile t+1 landed everywhere
    compute_tile(LA1, LB1, wm, wn, lr, lg, acc);
    BAR(); SCH0();
    stage_tile(Ag, Bg, Kstr, t + 3, LA1, LB1, tid);
    VMCNT8(); BAR(); SCH0();
  }
  compute_tile(LA0, LB0, wm, wn, lr, lg, acc);   // tile T-2
  VMCNT0(); BAR(); SCH0();                       // tile T-1 landed
  compute_tile(LA1, LB1, wm, wn, lr, lg, acc);   // tile T-1

#pragma unroll
  for (int m = 0; m < 8; ++m)
#pragma unroll
    for (int n = 0; n < 4; ++n)
#pragma unroll
      for (int r = 0; r < 4; ++r) {
        const int row = m0 + wm * 128 + m * 16 + lg * 4 + r;
        const int col = n0 + wn * 64 + n * 16 + lr;
        float val = acc[m][n][r];
        if (EPI == 0) {
          const int which = col >> 10, hc = col & 1023;
          const float* bs = (which == 0) ? bias0 : (which == 1) ? bias1 : bias2;
          bf16* dst = (which == 0) ? q_out : (which == 1) ? k_out : v_out;
          val += bs[hc];
          const int b = row >> 11, s = row & 2047;
          const int h = hc >> 6, hd = hc & 63;
          dst[(((size_t)b * 16 + h) * 2048 + s) * 64 + hd] = (bf16)val;
        } else if (EPI == 1) {
          pout[(size_t)bz * 4096 * 1024 + (size_t)row * 1024 + col] = val;
        } else {
          val += bias0[col];
          outb[(size_t)row * Nn + col] = (bf16)(val > 0.f ? val : 0.f);
        }
      }
}

// -------- split-K GEMM, 128x128 tile, N=1024: partial fp32, no bias --------
__global__ __launch_bounds__(256) void gemm_sk(
    const bf16* __restrict__ A, const bf16* __restrict__ Bt,
    int Kstride, int Kloop, int nbx, float* __restrict__ pout) {
  __shared__ __align__(16) bf16 As[128 * 32];
  __shared__ __align__(16) bf16 Bs[128 * 32];
  const int bz = blockIdx.y;
  const bf16* Ab = A + (size_t)bz * Kloop;
  const bf16* Bb = Bt + (size_t)bz * Kloop;
  float* pb = pout + (size_t)bz * 4096 * 1024;
  const int cpx = gridDim.x >> 3;
  const int wg = (blockIdx.x & 7) * cpx + (blockIdx.x >> 3);
  const int bx = wg % nbx, by = wg / nbx;
  const int tid = threadIdx.x;
  const int lane = tid & 63;
  const int wave = tid >> 6;
  const int lr = lane & 15, lg = lane >> 4;
  const int m0 = by * 128;
  const int n0 = bx * 128;
  const int wr = (wave >> 1) * 64, wc = (wave & 1) * 64;

  f32x4 acc[4][4] = {};

  const int idx0 = tid, idx1 = tid + 256;
  const char* gA0 = (const char*)(Ab + (size_t)(m0 + (idx0 >> 2)) * Kstride) + (idx0 & 3) * 16;
  const char* gA1 = (const char*)(Ab + (size_t)(m0 + (idx1 >> 2)) * Kstride) + (idx1 & 3) * 16;
  const char* gB0 = (const char*)(Bb + (size_t)(n0 + (idx0 >> 2)) * Kstride) + (idx0 & 3) * 16;
  const char* gB1 = (const char*)(Bb + (size_t)(n0 + (idx1 >> 2)) * Kstride) + (idx1 & 3) * 16;
  bf16* lA0 = &As[(wave * 64) * 8];
  bf16* lA1 = &As[(256 + wave * 64) * 8];
  bf16* lB0 = &Bs[(wave * 64) * 8];
  bf16* lB1 = &Bs[(256 + wave * 64) * 8];

  const int ksteps = Kloop >> 5;
  for (int kt = 0; kt < ksteps; ++kt) {
    load_lds16(gA0, lA0); load_lds16(gA1, lA1);
    load_lds16(gB0, lB0); load_lds16(gB1, lB1);
    gA0 += 64; gA1 += 64; gB0 += 64; gB1 += 64;
    __syncthreads();
    bf16x8 af[2], bfr[2];
    bf16x8 af2[2], bfr2[2];
#pragma unroll
    for (int i = 0; i < 4; ++i) {
      bf16x8 a = *(const bf16x8*)&As[(wr + i * 16 + lr) * 32 + lg * 8];
      if (i < 2) af[i] = a; else af2[i - 2] = a;
    }
#pragma unroll
    for (int j = 0; j < 4; ++j) {
      bf16x8 b = *(const bf16x8*)&Bs[(wc + j * 16 + lr) * 32 + lg * 8];
      if (j < 2) bfr[j] = b; else bfr2[j - 2] = b;
    }
#pragma unroll
    for (int i = 0; i < 4; ++i)
#pragma unroll
      for (int j = 0; j < 4; ++j) {
        const bf16x8 a = (i < 2) ? af[i & 1] : af2[i & 1];
        const bf16x8 b = (j < 2) ? bfr[j & 1] : bfr2[j & 1];
        acc[i][j] = MFMA16(a, b, acc[i][j]);
      }
    __syncthreads();
  }

#pragma unroll
  for (int i = 0; i < 4; ++i)
#pragma unroll
    for (int j = 0; j < 4; ++j)
#pragma unroll
      for (int r = 0; r < 4; ++r) {
        const int row = m0 + wr + i * 16 + lg * 4 + r;
        const int col = n0 + wc + j * 16 + lr;
        pb[(size_t)row * 1024 + col] = acc[i][j][r];
      }
}

// ------------------------- flash attention (per b,h) ------------------------
__global__ __launch_bounds__(256) void attn_kernel(const bf16* __restrict__ q,
                                                   const bf16* __restrict__ k,
                                                   const bf16* __restrict__ vt,
                                                   bf16* __restrict__ ctxo) {
  __shared__ __align__(16) bf16 Kl[64][64];
  __shared__ __align__(16) bf16 Vt[64][64];   // rows = hd, cols = key
  __shared__ __align__(16) bf16 Pl[4][16][64];
  const int tid = threadIdx.x;
  const int lane = tid & 63, w = tid >> 6;
  const int lr = lane & 15, lg = lane >> 4;
  const int swz = lr & 7;
  const int bh = blockIdx.y;
  const int q0 = blockIdx.x * 64;

  const bf16* qp = q + ((size_t)bh * 2048 + q0 + w * 16) * 64;
  bf16x8 qf0 = *(const bf16x8*)&qp[lr * 64 + lg * 8];
  bf16x8 qf1 = *(const bf16x8*)&qp[lr * 64 + lg * 8 + 32];
  const float qs = 0.18033688011112042f;      // (1/8)*log2(e)
#pragma unroll
  for (int j = 0; j < 8; ++j) {
    qf0[j] = (bf16)((float)qf0[j] * qs);
    qf1[j] = (bf16)((float)qf1[j] * qs);
  }
  bf16x8 ones8;
#pragma unroll
  for (int j = 0; j < 8; ++j) ones8[j] = (bf16)1.0f;

  const bf16* kbase = k + (size_t)bh * 2048 * 64;
  const bf16* vtb = vt + (size_t)bh * 64 * 2048;

  const int sr0 = tid >> 3, sr1 = sr0 + 32;
  const int c0 = (tid & 7) * 8;
  const int cs0 = c0 ^ ((sr0 & 7) << 3);
  const int cs1 = c0 ^ ((sr1 & 7) << 3);

  f32x4 acc[4] = {};
  f32x4 accl = {};
  float mq = -1e30f;

  bf16x8 kr[2][2], vr[2][2];
  kr[0][0] = *(const bf16x8*)&kbase[(size_t)sr0 * 64 + c0];
  kr[0][1] = *(const bf16x8*)&kbase[(size_t)sr1 * 64 + c0];
  vr[0][0] = *(const bf16x8*)&vtb[(size_t)sr0 * 2048 + c0];
  vr[0][1] = *(const bf16x8*)&vtb[(size_t)sr1 * 2048 + c0];

#pragma unroll 2
  for (int c = 0; c < 32; ++c) {
    const int pp = c & 1;
    *(bf16x8*)&Kl[sr0][cs0] = kr[pp][0];
    *(bf16x8*)&Kl[sr1][cs1] = kr[pp][1];
    *(bf16x8*)&Vt[sr0][cs0] = vr[pp][0];
    *(bf16x8*)&Vt[sr1][cs1] = vr[pp][1];
    if (c + 1 < 32) {
      const int key0n = (c + 1) * 64;
      kr[pp ^ 1][0] = *(const bf16x8*)&kbase[(size_t)(key0n + sr0) * 64 + c0];
      kr[pp ^ 1][1] = *(const bf16x8*)&kbase[(size_t)(key0n + sr1) * 64 + c0];
      vr[pp ^ 1][0] = *(const bf16x8*)&vtb[(size_t)sr0 * 2048 + key0n + c0];
      vr[pp ^ 1][1] = *(const bf16x8*)&vtb[(size_t)sr1 * 2048 + key0n + c0];
    }
    __syncthreads();

    f32x4 st[4];
    __builtin_amdgcn_s_setprio(1);
#pragma unroll
    for (int ks = 0; ks < 4; ++ks) {
      const bf16x8 kf0 = *(const bf16x8*)&Kl[ks * 16 + lr][(lg ^ swz) << 3];
      const bf16x8 kf1 = *(const bf16x8*)&Kl[ks * 16 + lr][((lg + 4) ^ swz) << 3];
      f32x4 sa = {};
      sa = MFMA16(kf0, qf0, sa);
      sa = MFMA16(kf1, qf1, sa);
      st[ks] = sa;
    }
    __builtin_amdgcn_s_setprio(0);

    // tree max (fuses to v_max3) instead of 16-deep serial chain
    float mk[4];
#pragma unroll
    for (int ks = 0; ks < 4; ++ks)
      mk[ks] = fmaxf(fmaxf(st[ks][0], st[ks][1]), fmaxf(st[ks][2], st[ks][3]));
    float mx = fmaxf(fmaxf(mk[0], mk[1]), fmaxf(mk[2], mk[3]));
    mx = fmaxf(mx, __shfl_xor(mx, 16));
    mx = fmaxf(mx, __shfl_xor(mx, 32));
    if (!__all(mx - mq <= 8.0f)) {
      const float resc = exp2f(mq - mx);
      mq = mx;
      float rq[4];
#pragma unroll
      for (int r = 0; r < 4; ++r) rq[r] = __shfl(resc, lg * 4 + r);
#pragma unroll
      for (int r = 0; r < 4; ++r) {
        accl[r] *= rq[r];
#pragma unroll
        for (int jn = 0; jn < 4; ++jn) acc[jn][r] *= rq[r];
      }
    }
#pragma unroll
    for (int ks = 0; ks < 4; ++ks) {
      bf16x4 pk;
#pragma unroll
      for (int r = 0; r < 4; ++r) pk[r] = (bf16)exp2f(st[ks][r] - mq);
      const int col = (((ks * 2 + (lg >> 1)) ^ swz) << 3) + ((lg & 1) << 2);
      *(bf16x4*)&Pl[w][lr][col] = pk;
    }

    const bf16x8 pf0 = *(const bf16x8*)&Pl[w][lr][(lg ^ swz) << 3];
    const bf16x8 pf1 = *(const bf16x8*)&Pl[w][lr][((lg + 4) ^ swz) << 3];
    __builtin_amdgcn_s_setprio(1);
#pragma unroll
    for (int jn = 0; jn < 4; ++jn) {
      const bf16x8 vf0 = *(const bf16x8*)&Vt[jn * 16 + lr][(lg ^ swz) << 3];
      const bf16x8 vf1 = *(const bf16x8*)&Vt[jn * 16 + lr][((lg + 4) ^ swz) << 3];
      acc[jn] = MFMA16(pf0, vf0, acc[jn]);
      acc[jn] = MFMA16(pf1, vf1, acc[jn]);
    }
    accl = MFMA16(pf0, ones8, accl);
    accl = MFMA16(pf1, ones8, accl);
    __builtin_amdgcn_s_setprio(0);
    __syncthreads();
  }

  const int bb = bh >> 4, hh = bh & 15;
#pragma unroll
  for (int r = 0; r < 4; ++r) {
    const float inv = 1.f / accl[r];
    const size_t rowg = (size_t)bb * 2048 + q0 + w * 16 + lg * 4 + r;
#pragma unroll
    for (int jn = 0; jn < 4; ++jn)
      ctxo[rowg * 1024 + hh * 64 + jn * 16 + lr] = (bf16)(acc[jn][r] * inv);
  }
}

// ---------- fused split-K reduce + bias + residual + LayerNorm --------------
template <int NP>
__global__ __launch_bounds__(256) void ln2_kernel(const float* __restrict__ p,
                                                  const bf16* __restrict__ resid,
                                                  const float* __restrict__ bias,
                                                  const float* __restrict__ g,
                                                  const float* __restrict__ be,
                                                  bf16* __restrict__ xo) {
  const int row = blockIdx.x, tid = threadIdx.x;
  const bf16x4 rv = *(const bf16x4*)&resid[(size_t)row * 1024 + tid * 4];
  const float4 bb = ((const float4*)bias)[tid];
  float4 v;
  v.x = bb.x + (float)rv[0];
  v.y = bb.y + (float)rv[1];
  v.z = bb.z + (float)rv[2];
  v.w = bb.w + (float)rv[3];
#pragma unroll
  for (int pl = 0; pl < NP; ++pl) {
    const float4 a = ((const float4*)(p + (size_t)pl * 4096 * 1024 + (size_t)row * 1024))[tid];
    v.x += a.x; v.y += a.y; v.z += a.z; v.w += a.w;
  }
  float s = v.x + v.y + v.z + v.w;
  float s2 = v.x * v.x + v.y * v.y + v.z * v.z + v.w * v.w;
#pragma unroll
  for (int o = 32; o > 0; o >>= 1) { s += __shfl_down(s, o); s2 += __shfl_down(s2, o); }
  __shared__ float red[8];
  if ((tid & 63) == 0) { red[tid >> 6] = s; red[4 + (tid >> 6)] = s2; }
  __syncthreads();
  s = red[0] + red[1] + red[2] + red[3];
  s2 = red[4] + red[5] + red[6] + red[7];
  const float mean = s * (1.f / 1024.f);
  const float var = s2 * (1.f / 1024.f) - mean * mean;
  const float rstd = rsqrtf(var + 1e-5f);
  const float4 gv = ((const float4*)g)[tid];
  const float4 bv = ((const float4*)be)[tid];
  bf16x4 o4;
  o4[0] = (bf16)((v.x - mean) * rstd * gv.x + bv.x);
  o4[1] = (bf16)((v.y - mean) * rstd * gv.y + bv.y);
  o4[2] = (bf16)((v.z - mean) * rstd * gv.z + bv.z);
  o4[3] = (bf16)((v.w - mean) * rstd * gv.w + bv.w);
  *(bf16x4*)&xo[(size_t)row * 1024 + tid * 4] = o4;
}

// ------------------------------ bf16 -> fp32 --------------------------------
__global__ __launch_bounds__(256) void to_f32_kernel(const bf16* __restrict__ x,
                                                     float* __restrict__ o) {
  const size_t i = ((size_t)blockIdx.x * 256 + threadIdx.x) * 4;
  const bf16x4 v = *(const bf16x4*)&x[i];
  float4 f;
  f.x = (float)v[0]; f.y = (float)v[1]; f.z = (float)v[2]; f.w = (float)v[3];
  *(float4*)&o[i] = f;
}

// ----------------------------------------------------------------------------
extern "C" void kernel_launch(void* const* d_in, const int* in_sizes, int n_in,
                              void* d_out, int out_size, void* d_ws, size_t ws_size,
                              hipStream_t stream) {
  const int* tokens = (const int*)d_in[0];
  const float* emb = (const float*)d_in[2];
  const float* Wq = (const float*)d_in[3];
  const float* bq = (const float*)d_in[4];
  const float* Wk = (const float*)d_in[5];
  const float* bk = (const float*)d_in[6];
  const float* Wv = (const float*)d_in[7];
  const float* bv = (const float*)d_in[8];
  const float* Wo = (const float*)d_in[9];
  const float* bo = (const float*)d_in[10];
  const float* W1 = (const float*)d_in[11];
  const float* b1 = (const float*)d_in[12];
  const float* W2 = (const float*)d_in[13];
  const float* b2 = (const float*)d_in[14];
  const float* g1 = (const float*)d_in[15];
  const float* be1 = (const float*)d_in[16];
  const float* g2 = (const float*)d_in[17];
  const float* be2 = (const float*)d_in[18];

  char* p = (char*)d_ws;
  auto carve = [&](size_t bytes) { char* r = p; p += (bytes + 255) & ~(size_t)255; return r; };
  bf16* wt_qkv = (bf16*)carve((size_t)3072 * 1024 * 2);
  bf16* wt_o   = (bf16*)carve((size_t)1024 * 1024 * 2);
  bf16* wt_1   = (bf16*)carve((size_t)4096 * 1024 * 2);
  bf16* wt_2   = (bf16*)carve((size_t)1024 * 4096 * 2);
  bf16* xb     = (bf16*)carve((size_t)4096 * 1024 * 2);
  bf16* qb     = (bf16*)carve((size_t)4096 * 1024 * 2);
  bf16* kb     = (bf16*)carve((size_t)4096 * 1024 * 2);
  bf16* vb     = (bf16*)carve((size_t)4096 * 1024 * 2);
  bf16* vtb    = (bf16*)carve((size_t)4096 * 1024 * 2);
  bf16* ctxb   = (bf16*)carve((size_t)4096 * 1024 * 2);
  float* pb    = (float*)carve((size_t)4 * 4096 * 1024 * 4);   // split-K partials
  bf16* hb     = (bf16*)carve((size_t)4096 * 4096 * 2);

  embed_kernel<<<4096, 256, 0, stream>>>(tokens, emb, xb);

  for (int l = 0; l < 6; ++l) {
    TArgs ta;
    ta.j[0] = { Wq + (size_t)l * 1024 * 1024, wt_qkv,                  1024, 1024, 0 };
    ta.j[1] = { Wk + (size_t)l * 1024 * 1024, wt_qkv + 1024 * 1024,    1024, 1024, 1024 };
    ta.j[2] = { Wv + (size_t)l * 1024 * 1024, wt_qkv + 2 * 1024 * 1024,1024, 1024, 2048 };
    ta.j[3] = { Wo + (size_t)l * 1024 * 1024, wt_o,                    1024, 1024, 3072 };
    ta.j[4] = { W1 + (size_t)l * 1024 * 4096, wt_1,                    1024, 4096, 4096 };
    ta.j[5] = { W2 + (size_t)l * 4096 * 1024, wt_2,                    4096, 1024, 8192 };
    wtrans_kernel<<<12288, 256, 0, stream>>>(ta);

    // QKV: 256^2 tile, grid 16x12 = 192
    gemm256<0><<<192, 512, 0, stream>>>(xb, wt_qkv, 1024, 1024, 3072, 12,
        bq + (size_t)l * 1024, bk + (size_t)l * 1024, bv + (size_t)l * 1024,
        nullptr, nullptr, qb, kb, vb);

    vtrans_kernel<<<dim3(32, 32), 256, 0, stream>>>(vb, vtb);

    attn_kernel<<<dim3(32, 32), 256, 0, stream>>>(qb, kb, vtb, ctxb);

    // O-proj: split-K=2 over K=1024 (128^2)
    gemm_sk<<<dim3(256, 2), 256, 0, stream>>>(ctxb, wt_o, 1024, 512, 8, pb);
    ln2_kernel<2><<<4096, 256, 0, stream>>>(pb, xb, bo + (size_t)l * 1024,
        g1 + (size_t)l * 1024, be1 + (size_t)l * 1024, xb);

    // FFN1: 256^2 tile, grid 16x16 = 256
    gemm256<2><<<256, 512, 0, stream>>>(xb, wt_1, 1024, 1024, 4096, 16,
        b1 + (size_t)l * 4096, nullptr, nullptr, hb,
        nullptr, nullptr, nullptr, nullptr);

    // FFN2: 256^2 tile split-K=4 (K-slice 1024), grid (64,4) = 256 blocks
    gemm256<1><<<dim3(64, 4), 512, 0, stream>>>(hb, wt_2, 4096, 1024, 1024, 4,
        nullptr, nullptr, nullptr, nullptr, pb,
        nullptr, nullptr, nullptr);
    ln2_kernel<4><<<4096, 256, 0, stream>>>(pb, xb, b2 + (size_t)l * 1024,
        g2 + (size_t)l * 1024, be2 + (size_t)l * 1024, xb);
  }

  to_f32_kernel<<<4096, 256, 0, stream>>>(xb, (float*)d_out);
}